// Round 6
// baseline (309.693 us; speedup 1.0000x reference)
//
#include <hip/hip_runtime.h>
#include <math.h>

#define EDGE_SCALE 0.17677669529663687f   // 32^-0.5
#define ATT_SCALE  0.15811388300841897f   // 40^-0.5
#define INV_ATT    6.324555320336759f     // sqrt(40)
#define LN_EPS 1e-5f

typedef __attribute__((ext_vector_type(8))) short bf8;
typedef __attribute__((ext_vector_type(4))) float f32x4;

__device__ __forceinline__ f32x4 mfma16(bf8 a, bf8 b, f32x4 c) {
  return __builtin_amdgcn_mfma_f32_16x16x32_bf16(a, b, c, 0, 0, 0);
}
__device__ __forceinline__ unsigned short f2bf(float f) {
  union { float f; unsigned u; } v; v.f = f;
  unsigned r = v.u + 0x7FFF + ((v.u >> 16) & 1);
  return (unsigned short)(r >> 16);
}
__device__ __forceinline__ float bf2f(unsigned short h) {
  union { unsigned u; float f; } v; v.u = ((unsigned)h) << 16;
  return v.f;
}
__device__ __forceinline__ float wave_max(float v) {
  #pragma unroll
  for (int o = 32; o > 0; o >>= 1) v = fmaxf(v, __shfl_xor(v, o));
  return v;
}
__device__ __forceinline__ float wave_sum(float v) {
  #pragma unroll
  for (int o = 32; o > 0; o >>= 1) v += __shfl_xor(v, o);
  return v;
}

// node[b,n,c] = x[b,c,n]; also bf16 copy
__global__ __launch_bounds__(256) void k_trans(const float* __restrict__ x,
    float* __restrict__ node, unsigned short* __restrict__ nodebf) {
  __shared__ float tile[32][33];
  const int b = blockIdx.z;
  const int n0 = blockIdx.x * 32, c0 = blockIdx.y * 32;
  const int tx = threadIdx.x & 31, ty = threadIdx.x >> 5;
  #pragma unroll
  for (int k = 0; k < 4; ++k) {
    int c = c0 + ty + 8 * k;
    tile[ty + 8 * k][tx] = x[((size_t)b * 320 + c) * 1024 + n0 + tx];
  }
  __syncthreads();
  #pragma unroll
  for (int k = 0; k < 4; ++k) {
    int n = n0 + ty + 8 * k;
    float v = tile[tx][ty + 8 * k];
    size_t idx = ((size_t)b * 1024 + n) * 320 + c0 + tx;
    node[idx] = v;
    nodebf[idx] = f2bf(v);
  }
}

__global__ __launch_bounds__(320) void k_svec(const float* __restrict__ da,
    const float* __restrict__ fw, const float* __restrict__ fb, float* __restrict__ sv) {
  __shared__ float ds[64];
  const int b = blockIdx.x, t = threadIdx.x;
  if (t < 64) {
    float a = 0.f;
    #pragma unroll
    for (int i = 0; i < 16; ++i) a += da[b * 1024 + i * 64 + t];
    ds[t] = a;
  }
  __syncthreads();
  if (t < 320) {
    float acc = 16.f * fb[t];
    #pragma unroll
    for (int e = 0; e < 64; ++e) acc = fmaf(ds[e], fw[t * 64 + e], acc);
    sv[b * 320 + t] = acc;
  }
}

// convert weights fp32->bf16 (qk_w | qkv_w | proj_w concatenated)
__global__ void k_wcvt(const float* __restrict__ a, int na,
                       const float* __restrict__ b, int nb,
                       const float* __restrict__ c, int nc,
                       unsigned short* __restrict__ out) {
  int tot = na + nb + nc;
  for (int i = blockIdx.x * blockDim.x + threadIdx.x; i < tot; i += gridDim.x * blockDim.x) {
    float v = (i < na) ? a[i] : ((i < na + nb) ? b[i - na] : c[i - na - nb]);
    out[i] = f2bf(v);
  }
}

// MFMA GEMM: C[2048, Ncols] = A[2048,320]bf16 @ W[Ncols,320]bf16^T (+bias)
// mode 0: p0 fp32 [row*320+col]
// mode 1: col<320 -> qe bf16 [B,N,320]; else ke bf16 [B,N,320]
// mode 2: q->p0 [B,H,N,64]bf16 (d>=40 zero-padded); k->p1 same; v->p2 [B,H,48,1024]bf16
// mode 3: p0 fp32 [(b*320+col)*1024+n] via LDS transpose
__global__ __launch_bounds__(256, 4) void k_mgemm(
    const unsigned short* __restrict__ A, const unsigned short* __restrict__ W,
    const float* __restrict__ bias, void* p0, void* p1, void* p2, int mode) {
  __shared__ float smem[64 * 65];     // mode-3 fp32 tile / mode-2 v-tile (ushort view)
  const int t = threadIdx.x, w = t >> 6, lane = t & 63;
  const int q16 = lane >> 4, l16 = lane & 15;
  const int rt = blockIdx.x * 64, jt = blockIdx.y * 64;
  f32x4 acc[4];
  #pragma unroll
  for (int i = 0; i < 4; ++i)
    #pragma unroll
    for (int j = 0; j < 4; ++j) acc[i][j] = 0.f;
  const unsigned short* ap = A + (size_t)(rt + 16 * w + l16) * 320 + q16 * 8;
  const unsigned short* wp = W + (size_t)(jt + l16) * 320 + q16 * 8;
  for (int kc = 0; kc < 10; ++kc) {
    bf8 af = *(const bf8*)(ap + kc * 32);
    #pragma unroll
    for (int ct = 0; ct < 4; ++ct) {
      bf8 bf = *(const bf8*)(wp + (size_t)ct * 16 * 320 + kc * 32);
      acc[ct] = mfma16(af, bf, acc[ct]);
    }
  }
  if (mode == 0 || mode == 1) {
    #pragma unroll
    for (int ct = 0; ct < 4; ++ct) {
      int col = jt + ct * 16 + l16;
      float bv = bias ? bias[col] : 0.f;
      #pragma unroll
      for (int r = 0; r < 4; ++r) {
        int row = rt + 16 * w + q16 * 4 + r;
        float v = acc[ct][r] + bv;
        if (mode == 0) {
          ((float*)p0)[(size_t)row * 320 + col] = v;
        } else {
          if (col < 320) ((unsigned short*)p0)[(size_t)row * 320 + col] = f2bf(v);
          else           ((unsigned short*)p1)[(size_t)row * 320 + col - 320] = f2bf(v);
        }
      }
    }
  } else if (mode == 2) {
    const int part = jt / 320;       // uniform per block (320 % 64 == 0)
    if (part < 2) {
      unsigned short* dst = (unsigned short*)(part == 0 ? p0 : p1);
      #pragma unroll
      for (int ct = 0; ct < 4; ++ct) {
        int col = jt + ct * 16 + l16;
        float bv = bias[col];
        int rem = col - part * 320;
        int h = rem / 40, d = rem % 40;
        #pragma unroll
        for (int r = 0; r < 4; ++r) {
          int row = rt + 16 * w + q16 * 4 + r;
          int b = row >> 10, n = row & 1023;
          size_t base = (((size_t)b * 8 + h) * 1024 + n) * 64;
          dst[base + d] = f2bf(acc[ct][r] + bv);
          if (d < 24) dst[base + 40 + d] = 0;   // zero the K-pad
        }
      }
    } else {
      // v: stage [col][n] ushort tile, then write [B,H,48,1024] coalesced
      unsigned short* vt_t = (unsigned short*)smem;       // [64][72]
      #pragma unroll
      for (int ct = 0; ct < 4; ++ct) {
        int col = jt + ct * 16 + l16;
        float bv = bias[col];
        #pragma unroll
        for (int r = 0; r < 4; ++r)
          vt_t[(ct * 16 + l16) * 72 + 16 * w + q16 * 4 + r] = f2bf(acc[ct][r] + bv);
      }
      __syncthreads();
      const int cl = t >> 2, seg = t & 3;
      int rem = (jt - 640) + cl;
      int h = rem / 40, d = rem % 40;
      int b = rt >> 10, n = (rt & 1023) + seg * 16;
      const float4* lp = (const float4*)&vt_t[cl * 72 + seg * 16];
      float4 a0 = lp[0], a1 = lp[1];
      float4* gp = (float4*)((unsigned short*)p2 +
                             (((size_t)b * 8 + h) * 48 + d) * 1024 + n);
      gp[0] = a0; gp[1] = a1;
    }
  } else {
    // mode 3: out[(b*320+col)*1024+n] via LDS transpose
    #pragma unroll
    for (int ct = 0; ct < 4; ++ct) {
      int col = jt + ct * 16 + l16;
      float bv = bias[col];
      #pragma unroll
      for (int r = 0; r < 4; ++r)
        smem[(16 * w + q16 * 4 + r) * 65 + ct * 16 + l16] = acc[ct][r] + bv;
    }
    __syncthreads();
    const int cl = t >> 2, seg = t & 3;
    int b = rt >> 10, n = (rt & 1023) + seg * 16;
    float* orow = (float*)p0 + ((size_t)b * 320 + jt + cl) * 1024 + n;
    #pragma unroll
    for (int i2 = 0; i2 < 4; ++i2) {
      float4 vv;
      vv.x = smem[(seg * 16 + i2 * 4 + 0) * 65 + cl];
      vv.y = smem[(seg * 16 + i2 * 4 + 1) * 65 + cl];
      vv.z = smem[(seg * 16 + i2 * 4 + 2) * 65 + cl];
      vv.w = smem[(seg * 16 + i2 * 4 + 3) * 65 + cl];
      ((float4*)orow)[i2] = vv;
    }
  }
}

// S[b,n,m] = (qe[b] @ ke[b]^T) * EDGE_SCALE   (batched MFMA GEMM, 512 blocks)
__global__ __launch_bounds__(256, 4) void k_sgemm(
    const unsigned short* __restrict__ qe, const unsigned short* __restrict__ ke,
    float* __restrict__ S) {
  const int t = threadIdx.x, w = t >> 6, lane = t & 63;
  const int q16 = lane >> 4, l16 = lane & 15;
  const int rt = blockIdx.x * 64, jt = blockIdx.y * 64, b = blockIdx.z;
  const unsigned short* A = qe + (size_t)b * 1024 * 320;
  const unsigned short* W = ke + (size_t)b * 1024 * 320;
  f32x4 acc[4];
  #pragma unroll
  for (int i = 0; i < 4; ++i)
    #pragma unroll
    for (int j = 0; j < 4; ++j) acc[i][j] = 0.f;
  const unsigned short* ap = A + (size_t)(rt + 16 * w + l16) * 320 + q16 * 8;
  const unsigned short* wp = W + (size_t)(jt + l16) * 320 + q16 * 8;
  for (int kc = 0; kc < 10; ++kc) {
    bf8 af = *(const bf8*)(ap + kc * 32);
    #pragma unroll
    for (int ct = 0; ct < 4; ++ct) {
      bf8 bf = *(const bf8*)(wp + (size_t)ct * 16 * 320 + kc * 32);
      acc[ct] = mfma16(af, bf, acc[ct]);
    }
  }
  #pragma unroll
  for (int ct = 0; ct < 4; ++ct)
    #pragma unroll
    for (int r = 0; r < 4; ++r)
      S[((size_t)b * 1024 + rt + 16 * w + q16 * 4 + r) * 1024 + jt + ct * 16 + l16] =
          acc[ct][r] * EDGE_SCALE;
}

// edge[row,:] = softmax(S[row,:])  (wave per row)
__global__ __launch_bounds__(256) void k_smax(const float* __restrict__ S,
                                              float* __restrict__ edge) {
  const int w = threadIdx.x >> 6, lane = threadIdx.x & 63;
  const int row = blockIdx.x * 4 + w;
  const float4* sp = (const float4*)(S + (size_t)row * 1024) + lane;
  float4 v[4];
  #pragma unroll
  for (int i = 0; i < 4; ++i) v[i] = sp[i * 64];
  float mx = -3.4e38f;
  #pragma unroll
  for (int i = 0; i < 4; ++i)
    mx = fmaxf(mx, fmaxf(fmaxf(v[i].x, v[i].y), fmaxf(v[i].z, v[i].w)));
  mx = wave_max(mx);
  float s = 0.f;
  #pragma unroll
  for (int i = 0; i < 4; ++i) {
    v[i].x = __expf(v[i].x - mx); v[i].y = __expf(v[i].y - mx);
    v[i].z = __expf(v[i].z - mx); v[i].w = __expf(v[i].w - mx);
    s += v[i].x + v[i].y + v[i].z + v[i].w;
  }
  s = wave_sum(s);
  float inv = 1.f / s;
  float4* ep = (float4*)(edge + (size_t)row * 1024) + lane;
  #pragma unroll
  for (int i = 0; i < 4; ++i)
    ep[i * 64] = make_float4(v[i].x * inv, v[i].y * inv, v[i].z * inv, v[i].w * inv);
}

// y_bf16 = LN(diag*LN(node)*s + LN(node)) per row; wave = 1 row.
__global__ __launch_bounds__(256) void k_ln(const float* __restrict__ node,
    const float* __restrict__ edge, const float* __restrict__ sv,
    const float* __restrict__ g1, const float* __restrict__ b1,
    const float* __restrict__ g2, const float* __restrict__ b2,
    unsigned short* __restrict__ y) {
  const int w = threadIdx.x >> 6, lane = threadIdx.x & 63;
  const int row = blockIdx.x * 4 + w;
  const int b = row >> 10, n = row & 1023;
  const float* xr = node + (size_t)row * 320;
  float x[5];
  #pragma unroll
  for (int i = 0; i < 5; ++i) x[i] = xr[lane + 64 * i];
  float s = x[0] + x[1] + x[2] + x[3] + x[4];
  float mean = wave_sum(s) * (1.f / 320.f);
  float v = 0.f;
  #pragma unroll
  for (int i = 0; i < 5; ++i) { float d = x[i] - mean; v += d * d; }
  float rstd = rsqrtf(wave_sum(v) * (1.f / 320.f) + LN_EPS);
  float diag = edge[(size_t)row * 1024 + n];
  float n2[5];
  #pragma unroll
  for (int i = 0; i < 5; ++i) {
    int c = lane + 64 * i;
    float nt = (x[i] - mean) * rstd * g1[c] + b1[c];
    n2[i] = diag * nt * sv[b * 320 + c] + nt;
  }
  s = n2[0] + n2[1] + n2[2] + n2[3] + n2[4];
  float mean2 = wave_sum(s) * (1.f / 320.f);
  v = 0.f;
  #pragma unroll
  for (int i = 0; i < 5; ++i) { float d = n2[i] - mean2; v += d * d; }
  float rstd2 = rsqrtf(wave_sum(v) * (1.f / 320.f) + LN_EPS);
  unsigned short* yr = y + (size_t)row * 320;
  #pragma unroll
  for (int i = 0; i < 5; ++i) {
    int c = lane + 64 * i;
    yr[c] = f2bf((n2[i] - mean2) * rstd2 * g2[c] + b2[c]);
  }
}

// Attention scores + softmax + AV per (b, h, 16-row tile).
// Writes att (AV, f32) and per-row softmax stats minv = {rowmax, 1/rowsum}.
// NO thbuf — the h-reduced t is recomputed by k_tred.
__global__ __launch_bounds__(256, 4) void k_score(
    const unsigned short* __restrict__ qbf, const unsigned short* __restrict__ kbf,
    const unsigned short* __restrict__ vtb, const float* __restrict__ edge,
    float* __restrict__ att, float2* __restrict__ minv,
    const float* __restrict__ ew, const float* __restrict__ eb) {
  __shared__ unsigned short a_lds[4][4][16][20];  // [wave][tile-in-group][n-row][m pad]
  __shared__ float ored[4][3][16][17];
  __shared__ float redm[4][16], reds[4][16];
  const int t = threadIdx.x, w = t >> 6, lane = t & 63;
  const int q16 = lane >> 4, l16 = lane & 15;
  const int n0 = blockIdx.x * 16, h = blockIdx.y, b = blockIdx.z;
  const size_t bh = (size_t)b * 8 + h;
  const float ewh = ew[h], ebh = eb[h];
  // acc init from edge: acc = (ev*ewh + ebh) * sqrt(40); final *= ATT_SCALE
  // (this exact FP sequence is replicated in k_tred for bit-consistency)
  f32x4 acc[16];
  const float* ep = edge + ((size_t)b * 1024 + n0 + q16 * 4) * 1024 + w * 256 + l16;
  #pragma unroll
  for (int tt = 0; tt < 16; ++tt)
    #pragma unroll
    for (int r = 0; r < 4; ++r)
      acc[tt][r] = fmaf(ep[(size_t)r * 1024 + tt * 16], ewh, ebh) * INV_ATT;
  const unsigned short* qp = qbf + (bh * 1024 + n0 + l16) * 64 + q16 * 8;
  bf8 af0 = *(const bf8*)(qp);
  bf8 af1 = *(const bf8*)(qp + 32);
  const unsigned short* kp = kbf + (bh * 1024 + (size_t)w * 256 + l16) * 64 + q16 * 8;
  #pragma unroll
  for (int tt = 0; tt < 16; ++tt) {
    const unsigned short* kpt = kp + (size_t)tt * 16 * 64;
    bf8 b0 = *(const bf8*)(kpt);
    bf8 b1 = *(const bf8*)(kpt + 32);
    acc[tt] = mfma16(af0, b0, acc[tt]);
    acc[tt] = mfma16(af1, b1, acc[tt]);
  }
  #pragma unroll
  for (int tt = 0; tt < 16; ++tt)
    #pragma unroll
    for (int r = 0; r < 4; ++r) acc[tt][r] *= ATT_SCALE;
  // block-wide row max
  float pm[4] = {-3.4e38f, -3.4e38f, -3.4e38f, -3.4e38f};
  #pragma unroll
  for (int tt = 0; tt < 16; ++tt)
    #pragma unroll
    for (int r = 0; r < 4; ++r) pm[r] = fmaxf(pm[r], acc[tt][r]);
  #pragma unroll
  for (int r = 0; r < 4; ++r)
    #pragma unroll
    for (int o = 1; o <= 8; o <<= 1) pm[r] = fmaxf(pm[r], __shfl_xor(pm[r], o));
  if (l16 == 0) {
    #pragma unroll
    for (int r = 0; r < 4; ++r) redm[w][q16 * 4 + r] = pm[r];
  }
  __syncthreads();
  float m[4], ps[4] = {0.f, 0.f, 0.f, 0.f};
  #pragma unroll
  for (int r = 0; r < 4; ++r)
    m[r] = fmaxf(fmaxf(redm[0][q16 * 4 + r], redm[1][q16 * 4 + r]),
                 fmaxf(redm[2][q16 * 4 + r], redm[3][q16 * 4 + r]));
  #pragma unroll
  for (int tt = 0; tt < 16; ++tt)
    #pragma unroll
    for (int r = 0; r < 4; ++r) ps[r] += __expf(acc[tt][r] - m[r]);
  #pragma unroll
  for (int r = 0; r < 4; ++r)
    #pragma unroll
    for (int o = 1; o <= 8; o <<= 1) ps[r] += __shfl_xor(ps[r], o);
  if (l16 == 0) {
    #pragma unroll
    for (int r = 0; r < 4; ++r) reds[w][q16 * 4 + r] = ps[r];
  }
  __syncthreads();
  float inv[4];
  #pragma unroll
  for (int r = 0; r < 4; ++r)
    inv[r] = 1.f / (reds[0][q16 * 4 + r] + reds[1][q16 * 4 + r] +
                    reds[2][q16 * 4 + r] + reds[3][q16 * 4 + r]);
  if (w == 0 && l16 == 0) {
    #pragma unroll
    for (int r = 0; r < 4; ++r)
      minv[bh * 1024 + n0 + q16 * 4 + r] = make_float2(m[r], inv[r]);
  }
  // grouped: a->LDS, AV-MFMA (per-wave private, no barrier)
  f32x4 oacc[3];
  #pragma unroll
  for (int i = 0; i < 3; ++i)
    #pragma unroll
    for (int j = 0; j < 4; ++j) oacc[i][j] = 0.f;
  #pragma unroll
  for (int g = 0; g < 4; ++g) {
    #pragma unroll
    for (int ti = 0; ti < 4; ++ti) {
      int tt = g * 4 + ti;
      #pragma unroll
      for (int r = 0; r < 4; ++r) {
        float e = __expf(acc[tt][r] - m[r]);
        a_lds[w][ti][q16 * 4 + r][l16] = f2bf(e * inv[r]);
      }
    }
    #pragma unroll
    for (int kk = 0; kk < 2; ++kk) {
      const unsigned short* ap2 = &a_lds[w][kk * 2 + (q16 >> 1)][l16][(q16 & 1) * 8];
      short4 lo = *(const short4*)(ap2);
      short4 hi = *(const short4*)(ap2 + 4);
      bf8 afv = {lo.x, lo.y, lo.z, lo.w, hi.x, hi.y, hi.z, hi.w};
      int kc = w * 8 + g * 2 + kk;
      const unsigned short* vp = vtb + (bh * 48 + l16) * 1024 + (size_t)kc * 32 + q16 * 8;
      #pragma unroll
      for (int nt = 0; nt < 3; ++nt) {
        bf8 bfv = *(const bf8*)(vp + (size_t)nt * 16 * 1024);
        oacc[nt] = mfma16(afv, bfv, oacc[nt]);
      }
    }
  }
  #pragma unroll
  for (int nt = 0; nt < 3; ++nt)
    #pragma unroll
    for (int r = 0; r < 4; ++r) ored[w][nt][q16 * 4 + r][l16] = oacc[nt][r];
  __syncthreads();
  #pragma unroll
  for (int k = 0; k < 3; ++k) {
    int o = k * 256 + t;
    int nt = o >> 8, row = (o >> 4) & 15, col = o & 15;
    int dim = nt * 16 + col;
    float sum = ored[0][nt][row][col] + ored[1][nt][row][col] +
                ored[2][nt][row][col] + ored[3][nt][row][col];
    if (dim < 40)
      att[((size_t)b * 1024 + n0 + row) * 320 + h * 40 + dim] = sum;
  }
}

// Recompute S per head, t = sum_h rw*(a+s) + rb in f32 regs; edge += t; tbf = t (bf16).
// Grid 1024 blocks x 256 thr: (b, 16-row n-tile, 128-col m-slice); wave = 32 m-cols.
__global__ __launch_bounds__(256, 4) void k_tred(
    const unsigned short* __restrict__ qbf, const unsigned short* __restrict__ kbf,
    float* __restrict__ edge, const float2* __restrict__ minv,
    unsigned short* __restrict__ tbf,
    const float* __restrict__ ew, const float* __restrict__ eb,
    const float* __restrict__ rw, const float* __restrict__ rb) {
  const int t = threadIdx.x, w = t >> 6, lane = t & 63;
  const int q16 = lane >> 4, l16 = lane & 15;
  const int bid = blockIdx.x;
  const int b = bid >> 9, rest = bid & 511;
  const int n0 = (rest >> 3) * 16;
  const int m0 = (rest & 7) * 128 + w * 32;
  const float rbv = rb[0];
  float ev[2][4], tacc[2][4];
  const float* ep = edge + ((size_t)b * 1024 + n0 + q16 * 4) * 1024 + m0 + l16;
  #pragma unroll
  for (int tt = 0; tt < 2; ++tt)
    #pragma unroll
    for (int r = 0; r < 4; ++r) {
      ev[tt][r] = ep[(size_t)r * 1024 + tt * 16];
      tacc[tt][r] = rbv;
    }
  #pragma unroll 1
  for (int h = 0; h < 8; ++h) {
    const size_t bh = (size_t)b * 8 + h;
    const float ewh = ew[h], ebh = eb[h], rwh = rw[h];
    const unsigned short* qp = qbf + (bh * 1024 + n0 + l16) * 64 + q16 * 8;
    bf8 af0 = *(const bf8*)(qp);
    bf8 af1 = *(const bf8*)(qp + 32);
    const unsigned short* kp = kbf + (bh * 1024 + m0 + l16) * 64 + q16 * 8;
    float2 mv[4];
    #pragma unroll
    for (int r = 0; r < 4; ++r) mv[r] = minv[bh * 1024 + n0 + q16 * 4 + r];
    #pragma unroll
    for (int tt = 0; tt < 2; ++tt) {
      const unsigned short* kpt = kp + (size_t)tt * 16 * 64;
      bf8 b0 = *(const bf8*)(kpt);
      bf8 b1 = *(const bf8*)(kpt + 32);
      f32x4 acc;
      #pragma unroll
      for (int r = 0; r < 4; ++r) acc[r] = fmaf(ev[tt][r], ewh, ebh) * INV_ATT;
      acc = mfma16(af0, b0, acc);
      acc = mfma16(af1, b1, acc);
      #pragma unroll
      for (int r = 0; r < 4; ++r) {
        float s = acc[r] * ATT_SCALE;
        float a = __expf(s - mv[r].x) * mv[r].y;
        tacc[tt][r] += rwh * (a + s);
      }
    }
  }
  #pragma unroll
  for (int tt = 0; tt < 2; ++tt)
    #pragma unroll
    for (int r = 0; r < 4; ++r) {
      size_t idx = ((size_t)b * 1024 + n0 + q16 * 4 + r) * 1024 + m0 + tt * 16 + l16;
      float tv = tacc[tt][r];
      edge[idx] = ev[tt][r] + tv;
      tbf[idx] = f2bf(tv);
    }
}

// ws-softmax over t row -> wsum; attbf = att + wsum (bf16). Wave per row.
__global__ __launch_bounds__(256) void k_ws(
    const unsigned short* __restrict__ tbf, const float* __restrict__ att,
    unsigned short* __restrict__ attbf) {
  const int w = threadIdx.x >> 6, lane = threadIdx.x & 63;
  const int row = blockIdx.x * 4 + w;
  const unsigned short* tp = tbf + (size_t)row * 1024 + lane * 4;
  float tv[16];
  #pragma unroll
  for (int seg = 0; seg < 4; ++seg) {
    ushort4 u = *(const ushort4*)(tp + seg * 256);
    tv[seg * 4 + 0] = bf2f(u.x);
    tv[seg * 4 + 1] = bf2f(u.y);
    tv[seg * 4 + 2] = bf2f(u.z);
    tv[seg * 4 + 3] = bf2f(u.w);
  }
  float mx = -3.4e38f;
  #pragma unroll
  for (int i = 0; i < 16; ++i) mx = fmaxf(mx, tv[i]);
  mx = wave_max(mx);
  float s = 0.f, num = 0.f;
  #pragma unroll
  for (int i = 0; i < 16; ++i) {
    float e = __expf(tv[i] - mx);
    s += e; num += e * tv[i];
  }
  s = wave_sum(s); num = wave_sum(num);
  const float wsum = num / s;
  const float* ar = att + (size_t)row * 320;
  unsigned short* ao = attbf + (size_t)row * 320;
  #pragma unroll
  for (int i = 0; i < 5; ++i) {
    int c = lane + 64 * i;
    ao[c] = f2bf(ar[c] + wsum);
  }
}

extern "C" void kernel_launch(void* const* d_in, const int* in_sizes, int n_in,
                              void* d_out, int out_size, void* d_ws, size_t ws_size,
                              hipStream_t stream) {
  const float* x      = (const float*)d_in[0];
  const float* da     = (const float*)d_in[1];
  const float* qk_w   = (const float*)d_in[2];
  const float* fcp_w  = (const float*)d_in[3];
  const float* fcp_b  = (const float*)d_in[4];
  const float* ln1_g  = (const float*)d_in[5];
  const float* ln1_b  = (const float*)d_in[6];
  const float* gln_g  = (const float*)d_in[7];
  const float* gln_b  = (const float*)d_in[8];
  const float* qkv_w  = (const float*)d_in[9];
  const float* qkv_b  = (const float*)d_in[10];
  const float* proj_w = (const float*)d_in[11];
  const float* proj_b = (const float*)d_in[12];
  const float* exp_w  = (const float*)d_in[13];
  const float* exp_b  = (const float*)d_in[14];
  const float* red_w  = (const float*)d_in[15];
  const float* red_b  = (const float*)d_in[16];
  float* ws = (float*)d_ws;
  float* node  = ws + 0;                                   // 655360
  unsigned short* ybf   = (unsigned short*)(ws + 655360);  // 327680 fl
  float* attb  = ws + 983040;                              // 655360
  unsigned short* attbf = (unsigned short*)(ws + 1638400); // 327680 fl
  float* edge  = ws + 1966080;                             // 2097152
  float* svec  = ws + 4063232;                             // 640
  unsigned short* nodebf = (unsigned short*)(ws + 4063872);// 327680 fl
  unsigned short* qe   = (unsigned short*)(ws + 4391552);  // 327680 fl
  unsigned short* ke   = (unsigned short*)(ws + 4719232);  // 327680 fl
  unsigned short* qbf  = (unsigned short*)(ws + 5046912);  // 524288 fl
  unsigned short* kbf  = (unsigned short*)(ws + 5571200);  // 524288 fl
  unsigned short* vtb  = (unsigned short*)(ws + 6095488);  // 393216 fl
  unsigned short* wbf  = (unsigned short*)(ws + 6488704);  // 512000 fl
  unsigned short* tbf  = (unsigned short*)(ws + 7000704);  // 1048576 fl (2M bf16)
  float2* minv = (float2*)(ws + 7000704 + 1048576);        // 32768 fl
  float* sbuf = ws + 15389312;                             // 2097152
  float* out = (float*)d_out;
  unsigned short* qk_wb   = wbf;
  unsigned short* qkv_wb  = wbf + 204800;
  unsigned short* proj_wb = wbf + 819200;

  hipLaunchKernelGGL(k_trans, dim3(32, 10, 2), dim3(256), 0, stream, x, node, nodebf);
  hipLaunchKernelGGL(k_svec, dim3(2), dim3(320), 0, stream, da, fcp_w, fcp_b, svec);
  hipLaunchKernelGGL(k_wcvt, dim3(512), dim3(256), 0, stream,
                     qk_w, 204800, qkv_w, 614400, proj_w, 204800, wbf);
  hipLaunchKernelGGL(k_mgemm, dim3(32, 10), dim3(256), 0, stream,
                     nodebf, qk_wb, (const float*)nullptr, qe, ke, (void*)nullptr, 1);
  hipLaunchKernelGGL(k_sgemm, dim3(16, 16, 2), dim3(256), 0, stream, qe, ke, sbuf);
  hipLaunchKernelGGL(k_smax, dim3(512), dim3(256), 0, stream, sbuf, edge);
  for (int l = 0; l < 2; ++l) {
    hipLaunchKernelGGL(k_ln, dim3(512), dim3(256), 0, stream, node, edge, svec,
                       ln1_g + l * 320, ln1_b + l * 320, gln_g + l * 320, gln_b + l * 320, ybf);
    hipLaunchKernelGGL(k_mgemm, dim3(32, 15), dim3(256), 0, stream,
                       ybf, qkv_wb + (size_t)l * 307200, qkv_b + l * 960, qbf, kbf, vtb, 2);
    hipLaunchKernelGGL(k_score, dim3(64, 8, 2), dim3(256), 0, stream,
                       qbf, kbf, vtb, edge, attb, minv,
                       exp_w + l * 8, exp_b + l * 8);
    hipLaunchKernelGGL(k_tred, dim3(1024), dim3(256), 0, stream,
                       qbf, kbf, edge, minv, tbf,
                       exp_w + l * 8, exp_b + l * 8, red_w + l * 8, red_b + l);
    hipLaunchKernelGGL(k_ws, dim3(512), dim3(256), 0, stream, tbf, attb, attbf);
    if (l == 0)
      hipLaunchKernelGGL(k_mgemm, dim3(32, 5), dim3(256), 0, stream,
                         attbf, proj_wb, proj_b, node, (void*)nullptr, (void*)nullptr, 0);
    else
      hipLaunchKernelGGL(k_mgemm, dim3(32, 5), dim3(256), 0, stream,
                         attbf, proj_wb + 102400, proj_b + 320, out,
                         (void*)nullptr, (void*)nullptr, 3);
  }
}

// Round 7
// 299.009 us; speedup vs baseline: 1.0357x; 1.0357x over previous
//
#include <hip/hip_runtime.h>
#include <math.h>

#define EDGE_SCALE 0.17677669529663687f   // 32^-0.5
#define ATT_SCALE  0.15811388300841897f   // 40^-0.5
#define LN_EPS 1e-5f

typedef __attribute__((ext_vector_type(8))) short bf8;
typedef __attribute__((ext_vector_type(4))) float f32x4;

__device__ __forceinline__ f32x4 mfma16(bf8 a, bf8 b, f32x4 c) {
  return __builtin_amdgcn_mfma_f32_16x16x32_bf16(a, b, c, 0, 0, 0);
}
__device__ __forceinline__ unsigned short f2bf(float f) {
  union { float f; unsigned u; } v; v.f = f;
  unsigned r = v.u + 0x7FFF + ((v.u >> 16) & 1);
  return (unsigned short)(r >> 16);
}
__device__ __forceinline__ float bf2f(unsigned short h) {
  union { unsigned u; float f; } v; v.u = ((unsigned)h) << 16;
  return v.f;
}
__device__ __forceinline__ float wave_max(float v) {
  #pragma unroll
  for (int o = 32; o > 0; o >>= 1) v = fmaxf(v, __shfl_xor(v, o));
  return v;
}
__device__ __forceinline__ float wave_sum(float v) {
  #pragma unroll
  for (int o = 32; o > 0; o >>= 1) v += __shfl_xor(v, o);
  return v;
}

// node[b,n,c] = x[b,c,n]; also bf16 copy
__global__ __launch_bounds__(256) void k_trans(const float* __restrict__ x,
    float* __restrict__ node, unsigned short* __restrict__ nodebf) {
  __shared__ float tile[32][33];
  const int b = blockIdx.z;
  const int n0 = blockIdx.x * 32, c0 = blockIdx.y * 32;
  const int tx = threadIdx.x & 31, ty = threadIdx.x >> 5;
  #pragma unroll
  for (int k = 0; k < 4; ++k) {
    int c = c0 + ty + 8 * k;
    tile[ty + 8 * k][tx] = x[((size_t)b * 320 + c) * 1024 + n0 + tx];
  }
  __syncthreads();
  #pragma unroll
  for (int k = 0; k < 4; ++k) {
    int n = n0 + ty + 8 * k;
    float v = tile[tx][ty + 8 * k];
    size_t idx = ((size_t)b * 1024 + n) * 320 + c0 + tx;
    node[idx] = v;
    nodebf[idx] = f2bf(v);
  }
}

__global__ __launch_bounds__(320) void k_svec(const float* __restrict__ da,
    const float* __restrict__ fw, const float* __restrict__ fb, float* __restrict__ sv) {
  __shared__ float ds[64];
  const int b = blockIdx.x, t = threadIdx.x;
  if (t < 64) {
    float a = 0.f;
    #pragma unroll
    for (int i = 0; i < 16; ++i) a += da[b * 1024 + i * 64 + t];
    ds[t] = a;
  }
  __syncthreads();
  if (t < 320) {
    float acc = 16.f * fb[t];
    #pragma unroll
    for (int e = 0; e < 64; ++e) acc = fmaf(ds[e], fw[t * 64 + e], acc);
    sv[b * 320 + t] = acc;
  }
}

// convert weights fp32->bf16 (qk_w | qkv_w | proj_w concatenated)
__global__ void k_wcvt(const float* __restrict__ a, int na,
                       const float* __restrict__ b, int nb,
                       const float* __restrict__ c, int nc,
                       unsigned short* __restrict__ out) {
  int tot = na + nb + nc;
  for (int i = blockIdx.x * blockDim.x + threadIdx.x; i < tot; i += gridDim.x * blockDim.x) {
    float v = (i < na) ? a[i] : ((i < na + nb) ? b[i - na] : c[i - na - nb]);
    out[i] = f2bf(v);
  }
}

// MFMA GEMM: C[2048, Ncols] = A[2048,320]bf16 @ W[Ncols,320]bf16^T (+bias)
// mode 0: p0 fp32 [row*320+col]
// mode 1: col<320 -> qe bf16 [B,N,320]; else ke bf16 [B,N,320]
// mode 2: q->p0 [B,H,N,64]bf16 (d>=40 zero-padded); k->p1 same; v->p2 [B,H,48,1024]bf16
// mode 3: p0 fp32 [(b*320+col)*1024+n] via LDS transpose
__global__ __launch_bounds__(256, 4) void k_mgemm(
    const unsigned short* __restrict__ A, const unsigned short* __restrict__ W,
    const float* __restrict__ bias, void* p0, void* p1, void* p2, int mode) {
  __shared__ float smem[64 * 65];     // mode-3 fp32 tile / mode-2 v-tile (ushort view)
  const int t = threadIdx.x, w = t >> 6, lane = t & 63;
  const int q16 = lane >> 4, l16 = lane & 15;
  const int rt = blockIdx.x * 64, jt = blockIdx.y * 64;
  f32x4 acc[4];
  #pragma unroll
  for (int i = 0; i < 4; ++i)
    #pragma unroll
    for (int j = 0; j < 4; ++j) acc[i][j] = 0.f;
  const unsigned short* ap = A + (size_t)(rt + 16 * w + l16) * 320 + q16 * 8;
  const unsigned short* wp = W + (size_t)(jt + l16) * 320 + q16 * 8;
  for (int kc = 0; kc < 10; ++kc) {
    bf8 af = *(const bf8*)(ap + kc * 32);
    #pragma unroll
    for (int ct = 0; ct < 4; ++ct) {
      bf8 bf = *(const bf8*)(wp + (size_t)ct * 16 * 320 + kc * 32);
      acc[ct] = mfma16(af, bf, acc[ct]);
    }
  }
  if (mode == 0 || mode == 1) {
    #pragma unroll
    for (int ct = 0; ct < 4; ++ct) {
      int col = jt + ct * 16 + l16;
      float bv = bias ? bias[col] : 0.f;
      #pragma unroll
      for (int r = 0; r < 4; ++r) {
        int row = rt + 16 * w + q16 * 4 + r;
        float v = acc[ct][r] + bv;
        if (mode == 0) {
          ((float*)p0)[(size_t)row * 320 + col] = v;
        } else {
          if (col < 320) ((unsigned short*)p0)[(size_t)row * 320 + col] = f2bf(v);
          else           ((unsigned short*)p1)[(size_t)row * 320 + col - 320] = f2bf(v);
        }
      }
    }
  } else if (mode == 2) {
    const int part = jt / 320;       // uniform per block (320 % 64 == 0)
    if (part < 2) {
      unsigned short* dst = (unsigned short*)(part == 0 ? p0 : p1);
      #pragma unroll
      for (int ct = 0; ct < 4; ++ct) {
        int col = jt + ct * 16 + l16;
        float bv = bias[col];
        int rem = col - part * 320;
        int h = rem / 40, d = rem % 40;
        #pragma unroll
        for (int r = 0; r < 4; ++r) {
          int row = rt + 16 * w + q16 * 4 + r;
          int b = row >> 10, n = row & 1023;
          size_t base = (((size_t)b * 8 + h) * 1024 + n) * 64;
          dst[base + d] = f2bf(acc[ct][r] + bv);
          if (d < 24) dst[base + 40 + d] = 0;   // zero the K-pad
        }
      }
    } else {
      // v: stage [col][n] ushort tile, then write [B,H,48,1024] coalesced
      unsigned short* vt_t = (unsigned short*)smem;       // [64][72]
      #pragma unroll
      for (int ct = 0; ct < 4; ++ct) {
        int col = jt + ct * 16 + l16;
        float bv = bias[col];
        #pragma unroll
        for (int r = 0; r < 4; ++r)
          vt_t[(ct * 16 + l16) * 72 + 16 * w + q16 * 4 + r] = f2bf(acc[ct][r] + bv);
      }
      __syncthreads();
      const int cl = t >> 2, seg = t & 3;
      int rem = (jt - 640) + cl;
      int h = rem / 40, d = rem % 40;
      int b = rt >> 10, n = (rt & 1023) + seg * 16;
      const float4* lp = (const float4*)&vt_t[cl * 72 + seg * 16];
      float4 a0 = lp[0], a1 = lp[1];
      float4* gp = (float4*)((unsigned short*)p2 +
                             (((size_t)b * 8 + h) * 48 + d) * 1024 + n);
      gp[0] = a0; gp[1] = a1;
    }
  } else {
    // mode 3: out[(b*320+col)*1024+n] via LDS transpose
    #pragma unroll
    for (int ct = 0; ct < 4; ++ct) {
      int col = jt + ct * 16 + l16;
      float bv = bias[col];
      #pragma unroll
      for (int r = 0; r < 4; ++r)
        smem[(16 * w + q16 * 4 + r) * 65 + ct * 16 + l16] = acc[ct][r] + bv;
    }
    __syncthreads();
    const int cl = t >> 2, seg = t & 3;
    int b = rt >> 10, n = (rt & 1023) + seg * 16;
    float* orow = (float*)p0 + ((size_t)b * 320 + jt + cl) * 1024 + n;
    #pragma unroll
    for (int i2 = 0; i2 < 4; ++i2) {
      float4 vv;
      vv.x = smem[(seg * 16 + i2 * 4 + 0) * 65 + cl];
      vv.y = smem[(seg * 16 + i2 * 4 + 1) * 65 + cl];
      vv.z = smem[(seg * 16 + i2 * 4 + 2) * 65 + cl];
      vv.w = smem[(seg * 16 + i2 * 4 + 3) * 65 + cl];
      ((float4*)orow)[i2] = vv;
    }
  }
}

// S[b,n,m] = (qe[b] @ ke[b]^T) * EDGE_SCALE   (batched MFMA GEMM, 512 blocks)
__global__ __launch_bounds__(256, 4) void k_sgemm(
    const unsigned short* __restrict__ qe, const unsigned short* __restrict__ ke,
    float* __restrict__ S) {
  const int t = threadIdx.x, w = t >> 6, lane = t & 63;
  const int q16 = lane >> 4, l16 = lane & 15;
  const int rt = blockIdx.x * 64, jt = blockIdx.y * 64, b = blockIdx.z;
  const unsigned short* A = qe + (size_t)b * 1024 * 320;
  const unsigned short* W = ke + (size_t)b * 1024 * 320;
  f32x4 acc[4];
  #pragma unroll
  for (int i = 0; i < 4; ++i)
    #pragma unroll
    for (int j = 0; j < 4; ++j) acc[i][j] = 0.f;
  const unsigned short* ap = A + (size_t)(rt + 16 * w + l16) * 320 + q16 * 8;
  const unsigned short* wp = W + (size_t)(jt + l16) * 320 + q16 * 8;
  for (int kc = 0; kc < 10; ++kc) {
    bf8 af = *(const bf8*)(ap + kc * 32);
    #pragma unroll
    for (int ct = 0; ct < 4; ++ct) {
      bf8 bf = *(const bf8*)(wp + (size_t)ct * 16 * 320 + kc * 32);
      acc[ct] = mfma16(af, bf, acc[ct]);
    }
  }
  #pragma unroll
  for (int ct = 0; ct < 4; ++ct)
    #pragma unroll
    for (int r = 0; r < 4; ++r)
      S[((size_t)b * 1024 + rt + 16 * w + q16 * 4 + r) * 1024 + jt + ct * 16 + l16] =
          acc[ct][r] * EDGE_SCALE;
}

// edge[row,:] = softmax(S[row,:])  (wave per row)
__global__ __launch_bounds__(256) void k_smax(const float* __restrict__ S,
                                              float* __restrict__ edge) {
  const int w = threadIdx.x >> 6, lane = threadIdx.x & 63;
  const int row = blockIdx.x * 4 + w;
  const float4* sp = (const float4*)(S + (size_t)row * 1024) + lane;
  float4 v[4];
  #pragma unroll
  for (int i = 0; i < 4; ++i) v[i] = sp[i * 64];
  float mx = -3.4e38f;
  #pragma unroll
  for (int i = 0; i < 4; ++i)
    mx = fmaxf(mx, fmaxf(fmaxf(v[i].x, v[i].y), fmaxf(v[i].z, v[i].w)));
  mx = wave_max(mx);
  float s = 0.f;
  #pragma unroll
  for (int i = 0; i < 4; ++i) {
    v[i].x = __expf(v[i].x - mx); v[i].y = __expf(v[i].y - mx);
    v[i].z = __expf(v[i].z - mx); v[i].w = __expf(v[i].w - mx);
    s += v[i].x + v[i].y + v[i].z + v[i].w;
  }
  s = wave_sum(s);
  float inv = 1.f / s;
  float4* ep = (float4*)(edge + (size_t)row * 1024) + lane;
  #pragma unroll
  for (int i = 0; i < 4; ++i)
    ep[i * 64] = make_float4(v[i].x * inv, v[i].y * inv, v[i].z * inv, v[i].w * inv);
}

// y_bf16 = LN(diag*LN(node)*s + LN(node)) per row; wave = 1 row.
__global__ __launch_bounds__(256) void k_ln(const float* __restrict__ node,
    const float* __restrict__ edge, const float* __restrict__ sv,
    const float* __restrict__ g1, const float* __restrict__ b1,
    const float* __restrict__ g2, const float* __restrict__ b2,
    unsigned short* __restrict__ y) {
  const int w = threadIdx.x >> 6, lane = threadIdx.x & 63;
  const int row = blockIdx.x * 4 + w;
  const int b = row >> 10, n = row & 1023;
  const float* xr = node + (size_t)row * 320;
  float x[5];
  #pragma unroll
  for (int i = 0; i < 5; ++i) x[i] = xr[lane + 64 * i];
  float s = x[0] + x[1] + x[2] + x[3] + x[4];
  float mean = wave_sum(s) * (1.f / 320.f);
  float v = 0.f;
  #pragma unroll
  for (int i = 0; i < 5; ++i) { float d = x[i] - mean; v += d * d; }
  float rstd = rsqrtf(wave_sum(v) * (1.f / 320.f) + LN_EPS);
  float diag = edge[(size_t)row * 1024 + n];
  float n2[5];
  #pragma unroll
  for (int i = 0; i < 5; ++i) {
    int c = lane + 64 * i;
    float nt = (x[i] - mean) * rstd * g1[c] + b1[c];
    n2[i] = diag * nt * sv[b * 320 + c] + nt;
  }
  s = n2[0] + n2[1] + n2[2] + n2[3] + n2[4];
  float mean2 = wave_sum(s) * (1.f / 320.f);
  v = 0.f;
  #pragma unroll
  for (int i = 0; i < 5; ++i) { float d = n2[i] - mean2; v += d * d; }
  float rstd2 = rsqrtf(wave_sum(v) * (1.f / 320.f) + LN_EPS);
  unsigned short* yr = y + (size_t)row * 320;
  #pragma unroll
  for (int i = 0; i < 5; ++i) {
    int c = lane + 64 * i;
    yr[c] = f2bf((n2[i] - mean2) * rstd2 * g2[c] + b2[c]);
  }
}

// Attention scores + AV per (b, h, 16-row tile). MFMA, grouped LDS pipeline.
// Grid (8,64,2): h = blockIdx.x (fastest) so each XCD (round-robin on flat
// block ID) services only ~2 (b,h) pairs -> K/V L2-resident (~450 KB/XCD);
// edge rows stream via L3.
__global__ __launch_bounds__(256, 4) void k_score(
    const unsigned short* __restrict__ qbf, const unsigned short* __restrict__ kbf,
    const unsigned short* __restrict__ vtb, const float* __restrict__ edge,
    unsigned short* __restrict__ thbuf, float* __restrict__ att,
    const float* __restrict__ ew, const float* __restrict__ eb,
    const float* __restrict__ rw) {
  __shared__ unsigned short a_lds[4][4][16][20];  // [wave][tile-in-group][n-row][m pad]
  __shared__ unsigned short th_lds[4][16][72];    // [wave][n-row][64 m-cols pad72]
  __shared__ float ored[4][3][16][17];
  __shared__ float redm[4][16], reds[4][16];
  const int t = threadIdx.x, w = t >> 6, lane = t & 63;
  const int q16 = lane >> 4, l16 = lane & 15;
  const int h = blockIdx.x, n0 = blockIdx.y * 16, b = blockIdx.z;
  const size_t bh = (size_t)b * 8 + h;
  const unsigned short* qp = qbf + (bh * 1024 + n0 + l16) * 64 + q16 * 8;
  bf8 af0 = *(const bf8*)(qp);
  bf8 af1 = *(const bf8*)(qp + 32);
  f32x4 acc[16];
  #pragma unroll
  for (int i = 0; i < 16; ++i)
    #pragma unroll
    for (int j = 0; j < 4; ++j) acc[i][j] = 0.f;
  const unsigned short* kp = kbf + (bh * 1024 + (size_t)w * 256 + l16) * 64 + q16 * 8;
  #pragma unroll
  for (int tt = 0; tt < 16; ++tt) {
    const unsigned short* kpt = kp + (size_t)tt * 16 * 64;
    bf8 b0 = *(const bf8*)(kpt);
    bf8 b1 = *(const bf8*)(kpt + 32);
    acc[tt] = mfma16(af0, b0, acc[tt]);
    acc[tt] = mfma16(af1, b1, acc[tt]);
  }
  const float ewh = ew[h], ebh = eb[h], rwh = rw[h];
  const float* ep = edge + ((size_t)b * 1024 + n0 + q16 * 4) * 1024 + w * 256 + l16;
  #pragma unroll
  for (int tt = 0; tt < 16; ++tt)
    #pragma unroll
    for (int r = 0; r < 4; ++r) {
      float ev = ep[(size_t)r * 1024 + tt * 16];
      acc[tt][r] = fmaf(acc[tt][r], ATT_SCALE, fmaf(ev, ewh, ebh));
    }
  // block-wide row max
  float pm[4] = {-3.4e38f, -3.4e38f, -3.4e38f, -3.4e38f};
  #pragma unroll
  for (int tt = 0; tt < 16; ++tt)
    #pragma unroll
    for (int r = 0; r < 4; ++r) pm[r] = fmaxf(pm[r], acc[tt][r]);
  #pragma unroll
  for (int r = 0; r < 4; ++r)
    #pragma unroll
    for (int o = 1; o <= 8; o <<= 1) pm[r] = fmaxf(pm[r], __shfl_xor(pm[r], o));
  if (l16 == 0) {
    #pragma unroll
    for (int r = 0; r < 4; ++r) redm[w][q16 * 4 + r] = pm[r];
  }
  __syncthreads();
  float m[4], ps[4] = {0.f, 0.f, 0.f, 0.f};
  #pragma unroll
  for (int r = 0; r < 4; ++r)
    m[r] = fmaxf(fmaxf(redm[0][q16 * 4 + r], redm[1][q16 * 4 + r]),
                 fmaxf(redm[2][q16 * 4 + r], redm[3][q16 * 4 + r]));
  #pragma unroll
  for (int tt = 0; tt < 16; ++tt)
    #pragma unroll
    for (int r = 0; r < 4; ++r) ps[r] += __expf(acc[tt][r] - m[r]);
  #pragma unroll
  for (int r = 0; r < 4; ++r)
    #pragma unroll
    for (int o = 1; o <= 8; o <<= 1) ps[r] += __shfl_xor(ps[r], o);
  if (l16 == 0) {
    #pragma unroll
    for (int r = 0; r < 4; ++r) reds[w][q16 * 4 + r] = ps[r];
  }
  __syncthreads();
  float inv[4];
  #pragma unroll
  for (int r = 0; r < 4; ++r)
    inv[r] = 1.f / (reds[0][q16 * 4 + r] + reds[1][q16 * 4 + r] +
                    reds[2][q16 * 4 + r] + reds[3][q16 * 4 + r]);
  // grouped: a->LDS, th->LDS, AV-MFMA, th writeout (all per-wave private, no barrier)
  f32x4 oacc[3];
  #pragma unroll
  for (int i = 0; i < 3; ++i)
    #pragma unroll
    for (int j = 0; j < 4; ++j) oacc[i][j] = 0.f;
  unsigned short* tbase = thbuf + (bh * 1024 + n0) * 1024 + w * 256;
  const int trow = lane >> 2, tc4 = lane & 3;
  #pragma unroll
  for (int g = 0; g < 4; ++g) {
    #pragma unroll
    for (int ti = 0; ti < 4; ++ti) {
      int tt = g * 4 + ti;
      #pragma unroll
      for (int r = 0; r < 4; ++r) {
        float e = __expf(acc[tt][r] - m[r]);
        float a = e * inv[r];
        a_lds[w][ti][q16 * 4 + r][l16] = f2bf(a);
        th_lds[w][q16 * 4 + r][ti * 16 + l16] = f2bf(rwh * (a + acc[tt][r]));
      }
    }
    #pragma unroll
    for (int kk = 0; kk < 2; ++kk) {
      const unsigned short* ap2 = &a_lds[w][kk * 2 + (q16 >> 1)][l16][(q16 & 1) * 8];
      short4 lo = *(const short4*)(ap2);
      short4 hi = *(const short4*)(ap2 + 4);
      bf8 afv = {lo.x, lo.y, lo.z, lo.w, hi.x, hi.y, hi.z, hi.w};
      int kc = w * 8 + g * 2 + kk;
      const unsigned short* vp = vtb + (bh * 48 + l16) * 1024 + (size_t)kc * 32 + q16 * 8;
      #pragma unroll
      for (int nt = 0; nt < 3; ++nt) {
        bf8 bfv = *(const bf8*)(vp + (size_t)nt * 16 * 1024);
        oacc[nt] = mfma16(afv, bfv, oacc[nt]);
      }
    }
    {
      const float4* lp = (const float4*)&th_lds[w][trow][tc4 * 16];
      float4 v0 = lp[0], v1 = lp[1];
      float4* gp = (float4*)(tbase + (size_t)trow * 1024 + g * 64 + tc4 * 16);
      gp[0] = v0; gp[1] = v1;
    }
  }
  #pragma unroll
  for (int nt = 0; nt < 3; ++nt)
    #pragma unroll
    for (int r = 0; r < 4; ++r) ored[w][nt][q16 * 4 + r][l16] = oacc[nt][r];
  __syncthreads();
  #pragma unroll
  for (int k = 0; k < 3; ++k) {
    int o = k * 256 + t;
    int nt = o >> 8, row = (o >> 4) & 15, col = o & 15;
    int dim = nt * 16 + col;
    float sum = ored[0][nt][row][col] + ored[1][nt][row][col] +
                ored[2][nt][row][col] + ored[3][nt][row][col];
    if (dim < 40)
      att[((size_t)b * 1024 + n0 + row) * 320 + h * 40 + dim] = sum;
  }
}

// reduce thbuf over h -> t; edge += t; ws-softmax -> wsum; attbf = att + wsum (bf16)
__global__ __launch_bounds__(256) void k_wsum(
    const unsigned short* __restrict__ thbuf, float* __restrict__ edge,
    const float* __restrict__ att, unsigned short* __restrict__ attbf,
    const float* __restrict__ rb) {
  const int w = threadIdx.x >> 6, lane = threadIdx.x & 63;
  const int row = blockIdx.x * 4 + w;
  const int b = row >> 10, n = row & 1023;
  const float rbv = rb[0];
  float tv[16];
  #pragma unroll
  for (int i = 0; i < 16; ++i) tv[i] = rbv;
  #pragma unroll 1
  for (int h = 0; h < 8; ++h) {
    const unsigned short* tph = thbuf + (((size_t)b * 8 + h) * 1024 + n) * 1024 + lane * 4;
    #pragma unroll
    for (int seg = 0; seg < 4; ++seg) {
      ushort4 u = *(const ushort4*)(tph + seg * 256);
      tv[seg * 4 + 0] += bf2f(u.x);
      tv[seg * 4 + 1] += bf2f(u.y);
      tv[seg * 4 + 2] += bf2f(u.z);
      tv[seg * 4 + 3] += bf2f(u.w);
    }
  }
  float4* erp = (float4*)(edge + ((size_t)b * 1024 + n) * 1024) + lane;
  #pragma unroll
  for (int seg = 0; seg < 4; ++seg) {
    float4 e = erp[seg * 64];
    e.x += tv[seg * 4 + 0]; e.y += tv[seg * 4 + 1];
    e.z += tv[seg * 4 + 2]; e.w += tv[seg * 4 + 3];
    erp[seg * 64] = e;
  }
  float mx = -3.4e38f;
  #pragma unroll
  for (int i = 0; i < 16; ++i) mx = fmaxf(mx, tv[i]);
  mx = wave_max(mx);
  float s = 0.f, num = 0.f;
  #pragma unroll
  for (int i = 0; i < 16; ++i) {
    float e = __expf(tv[i] - mx);
    s += e; num += e * tv[i];
  }
  s = wave_sum(s); num = wave_sum(num);
  const float wsum = num / s;
  const float* ar = att + (size_t)row * 320;
  unsigned short* ao = attbf + (size_t)row * 320;
  #pragma unroll
  for (int i = 0; i < 5; ++i) {
    int c = lane + 64 * i;
    ao[c] = f2bf(ar[c] + wsum);
  }
}

extern "C" void kernel_launch(void* const* d_in, const int* in_sizes, int n_in,
                              void* d_out, int out_size, void* d_ws, size_t ws_size,
                              hipStream_t stream) {
  const float* x      = (const float*)d_in[0];
  const float* da     = (const float*)d_in[1];
  const float* qk_w   = (const float*)d_in[2];
  const float* fcp_w  = (const float*)d_in[3];
  const float* fcp_b  = (const float*)d_in[4];
  const float* ln1_g  = (const float*)d_in[5];
  const float* ln1_b  = (const float*)d_in[6];
  const float* gln_g  = (const float*)d_in[7];
  const float* gln_b  = (const float*)d_in[8];
  const float* qkv_w  = (const float*)d_in[9];
  const float* qkv_b  = (const float*)d_in[10];
  const float* proj_w = (const float*)d_in[11];
  const float* proj_b = (const float*)d_in[12];
  const float* exp_w  = (const float*)d_in[13];
  const float* exp_b  = (const float*)d_in[14];
  const float* red_w  = (const float*)d_in[15];
  const float* red_b  = (const float*)d_in[16];
  float* ws = (float*)d_ws;
  float* node  = ws + 0;                                   // 655360
  unsigned short* ybf   = (unsigned short*)(ws + 655360);  // 327680 fl
  float* attb  = ws + 983040;                              // 655360
  unsigned short* attbf = (unsigned short*)(ws + 1638400); // 327680 fl
  float* edge  = ws + 1966080;                             // 2097152
  float* svec  = ws + 4063232;                             // 640
  unsigned short* nodebf = (unsigned short*)(ws + 4063872);// 327680 fl
  unsigned short* qe   = (unsigned short*)(ws + 4391552);  // 327680 fl
  unsigned short* ke   = (unsigned short*)(ws + 4719232);  // 327680 fl
  unsigned short* qbf  = (unsigned short*)(ws + 5046912);  // 524288 fl
  unsigned short* kbf  = (unsigned short*)(ws + 5571200);  // 524288 fl
  unsigned short* vtb  = (unsigned short*)(ws + 6095488);  // 393216 fl
  unsigned short* wbf  = (unsigned short*)(ws + 6488704);  // 512000 fl
  unsigned short* thbuf= (unsigned short*)(ws + 7000704);  // 8388608 fl
  float* sbuf = ws + 15389312;                             // 2097152
  float* out = (float*)d_out;
  unsigned short* qk_wb   = wbf;
  unsigned short* qkv_wb  = wbf + 204800;
  unsigned short* proj_wb = wbf + 819200;

  hipLaunchKernelGGL(k_trans, dim3(32, 10, 2), dim3(256), 0, stream, x, node, nodebf);
  hipLaunchKernelGGL(k_svec, dim3(2), dim3(320), 0, stream, da, fcp_w, fcp_b, svec);
  hipLaunchKernelGGL(k_wcvt, dim3(512), dim3(256), 0, stream,
                     qk_w, 204800, qkv_w, 614400, proj_w, 204800, wbf);
  hipLaunchKernelGGL(k_mgemm, dim3(32, 10), dim3(256), 0, stream,
                     nodebf, qk_wb, (const float*)nullptr, qe, ke, (void*)nullptr, 1);
  hipLaunchKernelGGL(k_sgemm, dim3(16, 16, 2), dim3(256), 0, stream, qe, ke, sbuf);
  hipLaunchKernelGGL(k_smax, dim3(512), dim3(256), 0, stream, sbuf, edge);
  for (int l = 0; l < 2; ++l) {
    hipLaunchKernelGGL(k_ln, dim3(512), dim3(256), 0, stream, node, edge, svec,
                       ln1_g + l * 320, ln1_b + l * 320, gln_g + l * 320, gln_b + l * 320, ybf);
    hipLaunchKernelGGL(k_mgemm, dim3(32, 15), dim3(256), 0, stream,
                       ybf, qkv_wb + (size_t)l * 307200, qkv_b + l * 960, qbf, kbf, vtb, 2);
    hipLaunchKernelGGL(k_score, dim3(8, 64, 2), dim3(256), 0, stream,
                       qbf, kbf, vtb, edge, thbuf, attb,
                       exp_w + l * 8, exp_b + l * 8, red_w + l * 8);
    hipLaunchKernelGGL(k_wsum, dim3(512), dim3(256), 0, stream,
                       thbuf, edge, attb, attbf, red_b + l);
    if (l == 0)
      hipLaunchKernelGGL(k_mgemm, dim3(32, 5), dim3(256), 0, stream,
                         attbf, proj_wb, proj_b, node, (void*)nullptr, (void*)nullptr, 0);
    else
      hipLaunchKernelGGL(k_mgemm, dim3(32, 5), dim3(256), 0, stream,
                         attbf, proj_wb + 102400, proj_b + 320, out,
                         (void*)nullptr, (void*)nullptr, 3);
  }
}

// Round 8
// 294.058 us; speedup vs baseline: 1.0532x; 1.0168x over previous
//
#include <hip/hip_runtime.h>
#include <math.h>

#define EDGE_SCALE 0.17677669529663687f   // 32^-0.5
#define ATT_SCALE  0.15811388300841897f   // 40^-0.5
#define LN_EPS 1e-5f

typedef __attribute__((ext_vector_type(8))) short bf8;
typedef __attribute__((ext_vector_type(4))) float f32x4;

__device__ __forceinline__ f32x4 mfma16(bf8 a, bf8 b, f32x4 c) {
  return __builtin_amdgcn_mfma_f32_16x16x32_bf16(a, b, c, 0, 0, 0);
}
__device__ __forceinline__ unsigned short f2bf(float f) {
  union { float f; unsigned u; } v; v.f = f;
  unsigned r = v.u + 0x7FFF + ((v.u >> 16) & 1);
  return (unsigned short)(r >> 16);
}
__device__ __forceinline__ float bf2f(unsigned short h) {
  union { unsigned u; float f; } v; v.u = ((unsigned)h) << 16;
  return v.f;
}
__device__ __forceinline__ float wave_max(float v) {
  #pragma unroll
  for (int o = 32; o > 0; o >>= 1) v = fmaxf(v, __shfl_xor(v, o));
  return v;
}
__device__ __forceinline__ float wave_sum(float v) {
  #pragma unroll
  for (int o = 32; o > 0; o >>= 1) v += __shfl_xor(v, o);
  return v;
}

// node[b,n,c] = x[b,c,n]; also bf16 copy
__global__ __launch_bounds__(256) void k_trans(const float* __restrict__ x,
    float* __restrict__ node, unsigned short* __restrict__ nodebf) {
  __shared__ float tile[32][33];
  const int b = blockIdx.z;
  const int n0 = blockIdx.x * 32, c0 = blockIdx.y * 32;
  const int tx = threadIdx.x & 31, ty = threadIdx.x >> 5;
  #pragma unroll
  for (int k = 0; k < 4; ++k) {
    int c = c0 + ty + 8 * k;
    tile[ty + 8 * k][tx] = x[((size_t)b * 320 + c) * 1024 + n0 + tx];
  }
  __syncthreads();
  #pragma unroll
  for (int k = 0; k < 4; ++k) {
    int n = n0 + ty + 8 * k;
    float v = tile[tx][ty + 8 * k];
    size_t idx = ((size_t)b * 1024 + n) * 320 + c0 + tx;
    node[idx] = v;
    nodebf[idx] = f2bf(v);
  }
}

__global__ __launch_bounds__(320) void k_svec(const float* __restrict__ da,
    const float* __restrict__ fw, const float* __restrict__ fb, float* __restrict__ sv) {
  __shared__ float ds[64];
  const int b = blockIdx.x, t = threadIdx.x;
  if (t < 64) {
    float a = 0.f;
    #pragma unroll
    for (int i = 0; i < 16; ++i) a += da[b * 1024 + i * 64 + t];
    ds[t] = a;
  }
  __syncthreads();
  if (t < 320) {
    float acc = 16.f * fb[t];
    #pragma unroll
    for (int e = 0; e < 64; ++e) acc = fmaf(ds[e], fw[t * 64 + e], acc);
    sv[b * 320 + t] = acc;
  }
}

// convert weights fp32->bf16 (qk_w | qkv_w | proj_w concatenated)
__global__ void k_wcvt(const float* __restrict__ a, int na,
                       const float* __restrict__ b, int nb,
                       const float* __restrict__ c, int nc,
                       unsigned short* __restrict__ out) {
  int tot = na + nb + nc;
  for (int i = blockIdx.x * blockDim.x + threadIdx.x; i < tot; i += gridDim.x * blockDim.x) {
    float v = (i < na) ? a[i] : ((i < na + nb) ? b[i - na] : c[i - na - nb]);
    out[i] = f2bf(v);
  }
}

// MFMA GEMM: C[2048, Ncols] = A[2048,320]bf16 @ W[Ncols,320]bf16^T (+bias)
// mode 0: p0 fp32 [row*320+col]
// mode 1: col<320 -> qe bf16 [B,N,320]; else ke bf16 [B,N,320]
// mode 2: q->p0 [B,H,N,64]bf16 (d>=40 zero-padded); k->p1 same; v->p2 [B,H,48,1024]bf16
// mode 3: p0 fp32 [(b*320+col)*1024+n] via LDS transpose
__global__ __launch_bounds__(256, 4) void k_mgemm(
    const unsigned short* __restrict__ A, const unsigned short* __restrict__ W,
    const float* __restrict__ bias, void* p0, void* p1, void* p2, int mode) {
  __shared__ float smem[64 * 65];     // mode-3 fp32 tile / mode-2 v-tile (ushort view)
  const int t = threadIdx.x, w = t >> 6, lane = t & 63;
  const int q16 = lane >> 4, l16 = lane & 15;
  const int rt = blockIdx.x * 64, jt = blockIdx.y * 64;
  f32x4 acc[4];
  #pragma unroll
  for (int i = 0; i < 4; ++i)
    #pragma unroll
    for (int j = 0; j < 4; ++j) acc[i][j] = 0.f;
  const unsigned short* ap = A + (size_t)(rt + 16 * w + l16) * 320 + q16 * 8;
  const unsigned short* wp = W + (size_t)(jt + l16) * 320 + q16 * 8;
  for (int kc = 0; kc < 10; ++kc) {
    bf8 af = *(const bf8*)(ap + kc * 32);
    #pragma unroll
    for (int ct = 0; ct < 4; ++ct) {
      bf8 bf = *(const bf8*)(wp + (size_t)ct * 16 * 320 + kc * 32);
      acc[ct] = mfma16(af, bf, acc[ct]);
    }
  }
  if (mode == 0 || mode == 1) {
    #pragma unroll
    for (int ct = 0; ct < 4; ++ct) {
      int col = jt + ct * 16 + l16;
      float bv = bias ? bias[col] : 0.f;
      #pragma unroll
      for (int r = 0; r < 4; ++r) {
        int row = rt + 16 * w + q16 * 4 + r;
        float v = acc[ct][r] + bv;
        if (mode == 0) {
          ((float*)p0)[(size_t)row * 320 + col] = v;
        } else {
          if (col < 320) ((unsigned short*)p0)[(size_t)row * 320 + col] = f2bf(v);
          else           ((unsigned short*)p1)[(size_t)row * 320 + col - 320] = f2bf(v);
        }
      }
    }
  } else if (mode == 2) {
    const int part = jt / 320;       // uniform per block (320 % 64 == 0)
    if (part < 2) {
      unsigned short* dst = (unsigned short*)(part == 0 ? p0 : p1);
      #pragma unroll
      for (int ct = 0; ct < 4; ++ct) {
        int col = jt + ct * 16 + l16;
        float bv = bias[col];
        int rem = col - part * 320;
        int h = rem / 40, d = rem % 40;
        #pragma unroll
        for (int r = 0; r < 4; ++r) {
          int row = rt + 16 * w + q16 * 4 + r;
          int b = row >> 10, n = row & 1023;
          size_t base = (((size_t)b * 8 + h) * 1024 + n) * 64;
          dst[base + d] = f2bf(acc[ct][r] + bv);
          if (d < 24) dst[base + 40 + d] = 0;   // zero the K-pad
        }
      }
    } else {
      // v: stage [col][n] ushort tile, then write [B,H,48,1024] coalesced
      unsigned short* vt_t = (unsigned short*)smem;       // [64][72]
      #pragma unroll
      for (int ct = 0; ct < 4; ++ct) {
        int col = jt + ct * 16 + l16;
        float bv = bias[col];
        #pragma unroll
        for (int r = 0; r < 4; ++r)
          vt_t[(ct * 16 + l16) * 72 + 16 * w + q16 * 4 + r] = f2bf(acc[ct][r] + bv);
      }
      __syncthreads();
      const int cl = t >> 2, seg = t & 3;
      int rem = (jt - 640) + cl;
      int h = rem / 40, d = rem % 40;
      int b = rt >> 10, n = (rt & 1023) + seg * 16;
      const float4* lp = (const float4*)&vt_t[cl * 72 + seg * 16];
      float4 a0 = lp[0], a1 = lp[1];
      float4* gp = (float4*)((unsigned short*)p2 +
                             (((size_t)b * 8 + h) * 48 + d) * 1024 + n);
      gp[0] = a0; gp[1] = a1;
    }
  } else {
    // mode 3: out[(b*320+col)*1024+n] via LDS transpose
    #pragma unroll
    for (int ct = 0; ct < 4; ++ct) {
      int col = jt + ct * 16 + l16;
      float bv = bias[col];
      #pragma unroll
      for (int r = 0; r < 4; ++r)
        smem[(16 * w + q16 * 4 + r) * 65 + ct * 16 + l16] = acc[ct][r] + bv;
    }
    __syncthreads();
    const int cl = t >> 2, seg = t & 3;
    int b = rt >> 10, n = (rt & 1023) + seg * 16;
    float* orow = (float*)p0 + ((size_t)b * 320 + jt + cl) * 1024 + n;
    #pragma unroll
    for (int i2 = 0; i2 < 4; ++i2) {
      float4 vv;
      vv.x = smem[(seg * 16 + i2 * 4 + 0) * 65 + cl];
      vv.y = smem[(seg * 16 + i2 * 4 + 1) * 65 + cl];
      vv.z = smem[(seg * 16 + i2 * 4 + 2) * 65 + cl];
      vv.w = smem[(seg * 16 + i2 * 4 + 3) * 65 + cl];
      ((float4*)orow)[i2] = vv;
    }
  }
}

// S[b,n,m] = (qe[b] @ ke[b]^T) * EDGE_SCALE   (batched MFMA GEMM, 512 blocks)
__global__ __launch_bounds__(256, 4) void k_sgemm(
    const unsigned short* __restrict__ qe, const unsigned short* __restrict__ ke,
    float* __restrict__ S) {
  const int t = threadIdx.x, w = t >> 6, lane = t & 63;
  const int q16 = lane >> 4, l16 = lane & 15;
  const int rt = blockIdx.x * 64, jt = blockIdx.y * 64, b = blockIdx.z;
  const unsigned short* A = qe + (size_t)b * 1024 * 320;
  const unsigned short* W = ke + (size_t)b * 1024 * 320;
  f32x4 acc[4];
  #pragma unroll
  for (int i = 0; i < 4; ++i)
    #pragma unroll
    for (int j = 0; j < 4; ++j) acc[i][j] = 0.f;
  const unsigned short* ap = A + (size_t)(rt + 16 * w + l16) * 320 + q16 * 8;
  const unsigned short* wp = W + (size_t)(jt + l16) * 320 + q16 * 8;
  for (int kc = 0; kc < 10; ++kc) {
    bf8 af = *(const bf8*)(ap + kc * 32);
    #pragma unroll
    for (int ct = 0; ct < 4; ++ct) {
      bf8 bf = *(const bf8*)(wp + (size_t)ct * 16 * 320 + kc * 32);
      acc[ct] = mfma16(af, bf, acc[ct]);
    }
  }
  #pragma unroll
  for (int ct = 0; ct < 4; ++ct)
    #pragma unroll
    for (int r = 0; r < 4; ++r)
      S[((size_t)b * 1024 + rt + 16 * w + q16 * 4 + r) * 1024 + jt + ct * 16 + l16] =
          acc[ct][r] * EDGE_SCALE;
}

// edge[row,:] = softmax(S[row,:])  (wave per row)
__global__ __launch_bounds__(256) void k_smax(const float* __restrict__ S,
                                              float* __restrict__ edge) {
  const int w = threadIdx.x >> 6, lane = threadIdx.x & 63;
  const int row = blockIdx.x * 4 + w;
  const float4* sp = (const float4*)(S + (size_t)row * 1024) + lane;
  float4 v[4];
  #pragma unroll
  for (int i = 0; i < 4; ++i) v[i] = sp[i * 64];
  float mx = -3.4e38f;
  #pragma unroll
  for (int i = 0; i < 4; ++i)
    mx = fmaxf(mx, fmaxf(fmaxf(v[i].x, v[i].y), fmaxf(v[i].z, v[i].w)));
  mx = wave_max(mx);
  float s = 0.f;
  #pragma unroll
  for (int i = 0; i < 4; ++i) {
    v[i].x = __expf(v[i].x - mx); v[i].y = __expf(v[i].y - mx);
    v[i].z = __expf(v[i].z - mx); v[i].w = __expf(v[i].w - mx);
    s += v[i].x + v[i].y + v[i].z + v[i].w;
  }
  s = wave_sum(s);
  float inv = 1.f / s;
  float4* ep = (float4*)(edge + (size_t)row * 1024) + lane;
  #pragma unroll
  for (int i = 0; i < 4; ++i)
    ep[i * 64] = make_float4(v[i].x * inv, v[i].y * inv, v[i].z * inv, v[i].w * inv);
}

// y_bf16 = LN(diag*LN(node)*s + LN(node)) per row; wave = 1 row.
__global__ __launch_bounds__(256) void k_ln(const float* __restrict__ node,
    const float* __restrict__ edge, const float* __restrict__ sv,
    const float* __restrict__ g1, const float* __restrict__ b1,
    const float* __restrict__ g2, const float* __restrict__ b2,
    unsigned short* __restrict__ y) {
  const int w = threadIdx.x >> 6, lane = threadIdx.x & 63;
  const int row = blockIdx.x * 4 + w;
  const int b = row >> 10, n = row & 1023;
  const float* xr = node + (size_t)row * 320;
  float x[5];
  #pragma unroll
  for (int i = 0; i < 5; ++i) x[i] = xr[lane + 64 * i];
  float s = x[0] + x[1] + x[2] + x[3] + x[4];
  float mean = wave_sum(s) * (1.f / 320.f);
  float v = 0.f;
  #pragma unroll
  for (int i = 0; i < 5; ++i) { float d = x[i] - mean; v += d * d; }
  float rstd = rsqrtf(wave_sum(v) * (1.f / 320.f) + LN_EPS);
  float diag = edge[(size_t)row * 1024 + n];
  float n2[5];
  #pragma unroll
  for (int i = 0; i < 5; ++i) {
    int c = lane + 64 * i;
    float nt = (x[i] - mean) * rstd * g1[c] + b1[c];
    n2[i] = diag * nt * sv[b * 320 + c] + nt;
  }
  s = n2[0] + n2[1] + n2[2] + n2[3] + n2[4];
  float mean2 = wave_sum(s) * (1.f / 320.f);
  v = 0.f;
  #pragma unroll
  for (int i = 0; i < 5; ++i) { float d = n2[i] - mean2; v += d * d; }
  float rstd2 = rsqrtf(wave_sum(v) * (1.f / 320.f) + LN_EPS);
  unsigned short* yr = y + (size_t)row * 320;
  #pragma unroll
  for (int i = 0; i < 5; ++i) {
    int c = lane + 64 * i;
    yr[c] = f2bf((n2[i] - mean2) * rstd2 * g2[c] + b2[c]);
  }
}

// Attention scores + AV per (b, h, 16-row tile). MFMA, grouped LDS pipeline.
// R1 grid ordering (tile fastest) — best measured.
__global__ __launch_bounds__(256, 4) void k_score(
    const unsigned short* __restrict__ qbf, const unsigned short* __restrict__ kbf,
    const unsigned short* __restrict__ vtb, const float* __restrict__ edge,
    unsigned short* __restrict__ thbuf, float* __restrict__ att,
    const float* __restrict__ ew, const float* __restrict__ eb,
    const float* __restrict__ rw) {
  __shared__ unsigned short a_lds[4][4][16][20];  // [wave][tile-in-group][n-row][m pad]
  __shared__ unsigned short th_lds[4][16][72];    // [wave][n-row][64 m-cols pad72]
  __shared__ float ored[4][3][16][17];
  __shared__ float redm[4][16], reds[4][16];
  const int t = threadIdx.x, w = t >> 6, lane = t & 63;
  const int q16 = lane >> 4, l16 = lane & 15;
  const int n0 = blockIdx.x * 16, h = blockIdx.y, b = blockIdx.z;
  const size_t bh = (size_t)b * 8 + h;
  const unsigned short* qp = qbf + (bh * 1024 + n0 + l16) * 64 + q16 * 8;
  bf8 af0 = *(const bf8*)(qp);
  bf8 af1 = *(const bf8*)(qp + 32);
  f32x4 acc[16];
  #pragma unroll
  for (int i = 0; i < 16; ++i)
    #pragma unroll
    for (int j = 0; j < 4; ++j) acc[i][j] = 0.f;
  const unsigned short* kp = kbf + (bh * 1024 + (size_t)w * 256 + l16) * 64 + q16 * 8;
  #pragma unroll
  for (int tt = 0; tt < 16; ++tt) {
    const unsigned short* kpt = kp + (size_t)tt * 16 * 64;
    bf8 b0 = *(const bf8*)(kpt);
    bf8 b1 = *(const bf8*)(kpt + 32);
    acc[tt] = mfma16(af0, b0, acc[tt]);
    acc[tt] = mfma16(af1, b1, acc[tt]);
  }
  const float ewh = ew[h], ebh = eb[h], rwh = rw[h];
  const float* ep = edge + ((size_t)b * 1024 + n0 + q16 * 4) * 1024 + w * 256 + l16;
  #pragma unroll
  for (int tt = 0; tt < 16; ++tt)
    #pragma unroll
    for (int r = 0; r < 4; ++r) {
      float ev = ep[(size_t)r * 1024 + tt * 16];
      acc[tt][r] = fmaf(acc[tt][r], ATT_SCALE, fmaf(ev, ewh, ebh));
    }
  // block-wide row max
  float pm[4] = {-3.4e38f, -3.4e38f, -3.4e38f, -3.4e38f};
  #pragma unroll
  for (int tt = 0; tt < 16; ++tt)
    #pragma unroll
    for (int r = 0; r < 4; ++r) pm[r] = fmaxf(pm[r], acc[tt][r]);
  #pragma unroll
  for (int r = 0; r < 4; ++r)
    #pragma unroll
    for (int o = 1; o <= 8; o <<= 1) pm[r] = fmaxf(pm[r], __shfl_xor(pm[r], o));
  if (l16 == 0) {
    #pragma unroll
    for (int r = 0; r < 4; ++r) redm[w][q16 * 4 + r] = pm[r];
  }
  __syncthreads();
  float m[4], ps[4] = {0.f, 0.f, 0.f, 0.f};
  #pragma unroll
  for (int r = 0; r < 4; ++r)
    m[r] = fmaxf(fmaxf(redm[0][q16 * 4 + r], redm[1][q16 * 4 + r]),
                 fmaxf(redm[2][q16 * 4 + r], redm[3][q16 * 4 + r]));
  #pragma unroll
  for (int tt = 0; tt < 16; ++tt)
    #pragma unroll
    for (int r = 0; r < 4; ++r) ps[r] += __expf(acc[tt][r] - m[r]);
  #pragma unroll
  for (int r = 0; r < 4; ++r)
    #pragma unroll
    for (int o = 1; o <= 8; o <<= 1) ps[r] += __shfl_xor(ps[r], o);
  if (l16 == 0) {
    #pragma unroll
    for (int r = 0; r < 4; ++r) reds[w][q16 * 4 + r] = ps[r];
  }
  __syncthreads();
  float inv[4];
  #pragma unroll
  for (int r = 0; r < 4; ++r)
    inv[r] = 1.f / (reds[0][q16 * 4 + r] + reds[1][q16 * 4 + r] +
                    reds[2][q16 * 4 + r] + reds[3][q16 * 4 + r]);
  // grouped: a->LDS, th->LDS, AV-MFMA, th writeout (all per-wave private, no barrier)
  f32x4 oacc[3];
  #pragma unroll
  for (int i = 0; i < 3; ++i)
    #pragma unroll
    for (int j = 0; j < 4; ++j) oacc[i][j] = 0.f;
  unsigned short* tbase = thbuf + (bh * 1024 + n0) * 1024 + w * 256;
  const int trow = lane >> 2, tc4 = lane & 3;
  #pragma unroll
  for (int g = 0; g < 4; ++g) {
    #pragma unroll
    for (int ti = 0; ti < 4; ++ti) {
      int tt = g * 4 + ti;
      #pragma unroll
      for (int r = 0; r < 4; ++r) {
        float e = __expf(acc[tt][r] - m[r]);
        float a = e * inv[r];
        a_lds[w][ti][q16 * 4 + r][l16] = f2bf(a);
        th_lds[w][q16 * 4 + r][ti * 16 + l16] = f2bf(rwh * (a + acc[tt][r]));
      }
    }
    #pragma unroll
    for (int kk = 0; kk < 2; ++kk) {
      const unsigned short* ap2 = &a_lds[w][kk * 2 + (q16 >> 1)][l16][(q16 & 1) * 8];
      short4 lo = *(const short4*)(ap2);
      short4 hi = *(const short4*)(ap2 + 4);
      bf8 afv = {lo.x, lo.y, lo.z, lo.w, hi.x, hi.y, hi.z, hi.w};
      int kc = w * 8 + g * 2 + kk;
      const unsigned short* vp = vtb + (bh * 48 + l16) * 1024 + (size_t)kc * 32 + q16 * 8;
      #pragma unroll
      for (int nt = 0; nt < 3; ++nt) {
        bf8 bfv = *(const bf8*)(vp + (size_t)nt * 16 * 1024);
        oacc[nt] = mfma16(afv, bfv, oacc[nt]);
      }
    }
    {
      const float4* lp = (const float4*)&th_lds[w][trow][tc4 * 16];
      float4 v0 = lp[0], v1 = lp[1];
      float4* gp = (float4*)(tbase + (size_t)trow * 1024 + g * 64 + tc4 * 16);
      gp[0] = v0; gp[1] = v1;
    }
  }
  #pragma unroll
  for (int nt = 0; nt < 3; ++nt)
    #pragma unroll
    for (int r = 0; r < 4; ++r) ored[w][nt][q16 * 4 + r][l16] = oacc[nt][r];
  __syncthreads();
  #pragma unroll
  for (int k = 0; k < 3; ++k) {
    int o = k * 256 + t;
    int nt = o >> 8, row = (o >> 4) & 15, col = o & 15;
    int dim = nt * 16 + col;
    float sum = ored[0][nt][row][col] + ored[1][nt][row][col] +
                ored[2][nt][row][col] + ored[3][nt][row][col];
    if (dim < 40)
      att[((size_t)b * 1024 + n0 + row) * 320 + h * 40 + dim] = sum;
  }
}

// reduce thbuf over h -> t; edge += t; ws-softmax -> wsum; attbf = att + wsum (bf16)
// v2: 2 waves per row (512 cols each), h-loop unrolled (16 loads in flight),
// exact rescaled half-merge via LDS. Grid 1024 blocks -> 16 waves/CU.
__global__ __launch_bounds__(256) void k_wsum(
    const unsigned short* __restrict__ thbuf, float* __restrict__ edge,
    const float* __restrict__ att, unsigned short* __restrict__ attbf,
    const float* __restrict__ rb) {
  __shared__ float red[2][2][3];   // [row-in-block][half][max,sum,num]
  const int w = threadIdx.x >> 6, lane = threadIdx.x & 63;
  const int rw = w >> 1, half = w & 1;
  const int row = blockIdx.x * 2 + rw;
  const int b = row >> 10, n = row & 1023;
  const float rbv = rb[0];
  float tv[8];
  #pragma unroll
  for (int i = 0; i < 8; ++i) tv[i] = rbv;
  #pragma unroll
  for (int h = 0; h < 8; ++h) {
    const unsigned short* tph = thbuf + (((size_t)b * 8 + h) * 1024 + n) * 1024 +
                                half * 512 + lane * 4;
    #pragma unroll
    for (int seg = 0; seg < 2; ++seg) {
      ushort4 u = *(const ushort4*)(tph + seg * 256);
      tv[seg * 4 + 0] += bf2f(u.x);
      tv[seg * 4 + 1] += bf2f(u.y);
      tv[seg * 4 + 2] += bf2f(u.z);
      tv[seg * 4 + 3] += bf2f(u.w);
    }
  }
  float4* erp = (float4*)(edge + ((size_t)b * 1024 + n) * 1024 + half * 512) + lane;
  #pragma unroll
  for (int seg = 0; seg < 2; ++seg) {
    float4 e = erp[seg * 64];
    e.x += tv[seg * 4 + 0]; e.y += tv[seg * 4 + 1];
    e.z += tv[seg * 4 + 2]; e.w += tv[seg * 4 + 3];
    erp[seg * 64] = e;
  }
  float mx = -3.4e38f;
  #pragma unroll
  for (int i = 0; i < 8; ++i) mx = fmaxf(mx, tv[i]);
  mx = wave_max(mx);
  float s = 0.f, num = 0.f;
  #pragma unroll
  for (int i = 0; i < 8; ++i) {
    float e = __expf(tv[i] - mx);
    s += e; num += e * tv[i];
  }
  s = wave_sum(s); num = wave_sum(num);
  if (lane == 0) {
    red[rw][half][0] = mx;
    red[rw][half][1] = s;
    red[rw][half][2] = num;
  }
  __syncthreads();
  if (half == 0) {
    float m0 = red[rw][0][0], m1 = red[rw][1][0];
    float M = fmaxf(m0, m1);
    float e0 = __expf(m0 - M), e1 = __expf(m1 - M);
    float S = red[rw][0][1] * e0 + red[rw][1][1] * e1;
    float NUM = red[rw][0][2] * e0 + red[rw][1][2] * e1;
    const float wsum = NUM / S;
    const float* ar = att + (size_t)row * 320;
    unsigned short* ao = attbf + (size_t)row * 320;
    #pragma unroll
    for (int i = 0; i < 5; ++i) {
      int c = lane + 64 * i;
      ao[c] = f2bf(ar[c] + wsum);
    }
  }
}

extern "C" void kernel_launch(void* const* d_in, const int* in_sizes, int n_in,
                              void* d_out, int out_size, void* d_ws, size_t ws_size,
                              hipStream_t stream) {
  const float* x      = (const float*)d_in[0];
  const float* da     = (const float*)d_in[1];
  const float* qk_w   = (const float*)d_in[2];
  const float* fcp_w  = (const float*)d_in[3];
  const float* fcp_b  = (const float*)d_in[4];
  const float* ln1_g  = (const float*)d_in[5];
  const float* ln1_b  = (const float*)d_in[6];
  const float* gln_g  = (const float*)d_in[7];
  const float* gln_b  = (const float*)d_in[8];
  const float* qkv_w  = (const float*)d_in[9];
  const float* qkv_b  = (const float*)d_in[10];
  const float* proj_w = (const float*)d_in[11];
  const float* proj_b = (const float*)d_in[12];
  const float* exp_w  = (const float*)d_in[13];
  const float* exp_b  = (const float*)d_in[14];
  const float* red_w  = (const float*)d_in[15];
  const float* red_b  = (const float*)d_in[16];
  float* ws = (float*)d_ws;
  float* node  = ws + 0;                                   // 655360
  unsigned short* ybf   = (unsigned short*)(ws + 655360);  // 327680 fl
  float* attb  = ws + 983040;                              // 655360
  unsigned short* attbf = (unsigned short*)(ws + 1638400); // 327680 fl
  float* edge  = ws + 1966080;                             // 2097152
  float* svec  = ws + 4063232;                             // 640
  unsigned short* nodebf = (unsigned short*)(ws + 4063872);// 327680 fl
  unsigned short* qe   = (unsigned short*)(ws + 4391552);  // 327680 fl
  unsigned short* ke   = (unsigned short*)(ws + 4719232);  // 327680 fl
  unsigned short* qbf  = (unsigned short*)(ws + 5046912);  // 524288 fl
  unsigned short* kbf  = (unsigned short*)(ws + 5571200);  // 524288 fl
  unsigned short* vtb  = (unsigned short*)(ws + 6095488);  // 393216 fl
  unsigned short* wbf  = (unsigned short*)(ws + 6488704);  // 512000 fl
  unsigned short* thbuf= (unsigned short*)(ws + 7000704);  // 8388608 fl
  float* sbuf = ws + 15389312;                             // 2097152
  float* out = (float*)d_out;
  unsigned short* qk_wb   = wbf;
  unsigned short* qkv_wb  = wbf + 204800;
  unsigned short* proj_wb = wbf + 819200;

  hipLaunchKernelGGL(k_trans, dim3(32, 10, 2), dim3(256), 0, stream, x, node, nodebf);
  hipLaunchKernelGGL(k_svec, dim3(2), dim3(320), 0, stream, da, fcp_w, fcp_b, svec);
  hipLaunchKernelGGL(k_wcvt, dim3(512), dim3(256), 0, stream,
                     qk_w, 204800, qkv_w, 614400, proj_w, 204800, wbf);
  hipLaunchKernelGGL(k_mgemm, dim3(32, 10), dim3(256), 0, stream,
                     nodebf, qk_wb, (const float*)nullptr, qe, ke, (void*)nullptr, 1);
  hipLaunchKernelGGL(k_sgemm, dim3(16, 16, 2), dim3(256), 0, stream, qe, ke, sbuf);
  hipLaunchKernelGGL(k_smax, dim3(512), dim3(256), 0, stream, sbuf, edge);
  for (int l = 0; l < 2; ++l) {
    hipLaunchKernelGGL(k_ln, dim3(512), dim3(256), 0, stream, node, edge, svec,
                       ln1_g + l * 320, ln1_b + l * 320, gln_g + l * 320, gln_b + l * 320, ybf);
    hipLaunchKernelGGL(k_mgemm, dim3(32, 15), dim3(256), 0, stream,
                       ybf, qkv_wb + (size_t)l * 307200, qkv_b + l * 960, qbf, kbf, vtb, 2);
    hipLaunchKernelGGL(k_score, dim3(64, 8, 2), dim3(256), 0, stream,
                       qbf, kbf, vtb, edge, thbuf, attb,
                       exp_w + l * 8, exp_b + l * 8, red_w + l * 8);
    hipLaunchKernelGGL(k_wsum, dim3(1024), dim3(256), 0, stream,
                       thbuf, edge, attb, attbf, red_b + l);
    if (l == 0)
      hipLaunchKernelGGL(k_mgemm, dim3(32, 5), dim3(256), 0, stream,
                         attbf, proj_wb, proj_b, node, (void*)nullptr, (void*)nullptr, 0);
    else
      hipLaunchKernelGGL(k_mgemm, dim3(32, 5), dim3(256), 0, stream,
                         attbf, proj_wb + 102400, proj_b + 320, out,
                         (void*)nullptr, (void*)nullptr, 3);
  }
}

// Round 10
// 292.326 us; speedup vs baseline: 1.0594x; 1.0059x over previous
//
#include <hip/hip_runtime.h>
#include <math.h>

#define EDGE_SCALE 0.17677669529663687f   // 32^-0.5
#define ATT_SCALE  0.15811388300841897f   // 40^-0.5
#define LN_EPS 1e-5f

typedef __attribute__((ext_vector_type(8))) short bf8;
typedef __attribute__((ext_vector_type(4))) float f32x4;

__device__ __forceinline__ f32x4 mfma16(bf8 a, bf8 b, f32x4 c) {
  return __builtin_amdgcn_mfma_f32_16x16x32_bf16(a, b, c, 0, 0, 0);
}
__device__ __forceinline__ unsigned short f2bf(float f) {
  union { float f; unsigned u; } v; v.f = f;
  unsigned r = v.u + 0x7FFF + ((v.u >> 16) & 1);
  return (unsigned short)(r >> 16);
}
__device__ __forceinline__ float bf2f(unsigned short h) {
  union { unsigned u; float f; } v; v.u = ((unsigned)h) << 16;
  return v.f;
}
__device__ __forceinline__ float wave_max(float v) {
  #pragma unroll
  for (int o = 32; o > 0; o >>= 1) v = fmaxf(v, __shfl_xor(v, o));
  return v;
}
__device__ __forceinline__ float wave_sum(float v) {
  #pragma unroll
  for (int o = 32; o > 0; o >>= 1) v += __shfl_xor(v, o);
  return v;
}

// node[b,n,c] = x[b,c,n]; also bf16 copy
__global__ __launch_bounds__(256) void k_trans(const float* __restrict__ x,
    float* __restrict__ node, unsigned short* __restrict__ nodebf) {
  __shared__ float tile[32][33];
  const int b = blockIdx.z;
  const int n0 = blockIdx.x * 32, c0 = blockIdx.y * 32;
  const int tx = threadIdx.x & 31, ty = threadIdx.x >> 5;
  #pragma unroll
  for (int k = 0; k < 4; ++k) {
    int c = c0 + ty + 8 * k;
    tile[ty + 8 * k][tx] = x[((size_t)b * 320 + c) * 1024 + n0 + tx];
  }
  __syncthreads();
  #pragma unroll
  for (int k = 0; k < 4; ++k) {
    int n = n0 + ty + 8 * k;
    float v = tile[tx][ty + 8 * k];
    size_t idx = ((size_t)b * 1024 + n) * 320 + c0 + tx;
    node[idx] = v;
    nodebf[idx] = f2bf(v);
  }
}

__global__ __launch_bounds__(320) void k_svec(const float* __restrict__ da,
    const float* __restrict__ fw, const float* __restrict__ fb, float* __restrict__ sv) {
  __shared__ float ds[64];
  const int b = blockIdx.x, t = threadIdx.x;
  if (t < 64) {
    float a = 0.f;
    #pragma unroll
    for (int i = 0; i < 16; ++i) a += da[b * 1024 + i * 64 + t];
    ds[t] = a;
  }
  __syncthreads();
  if (t < 320) {
    float acc = 16.f * fb[t];
    #pragma unroll
    for (int e = 0; e < 64; ++e) acc = fmaf(ds[e], fw[t * 64 + e], acc);
    sv[b * 320 + t] = acc;
  }
}

// convert weights fp32->bf16 (qk_w | qkv_w | proj_w concatenated)
__global__ void k_wcvt(const float* __restrict__ a, int na,
                       const float* __restrict__ b, int nb,
                       const float* __restrict__ c, int nc,
                       unsigned short* __restrict__ out) {
  int tot = na + nb + nc;
  for (int i = blockIdx.x * blockDim.x + threadIdx.x; i < tot; i += gridDim.x * blockDim.x) {
    float v = (i < na) ? a[i] : ((i < na + nb) ? b[i - na] : c[i - na - nb]);
    out[i] = f2bf(v);
  }
}

// MFMA GEMM: C[2048, Ncols] = A[2048,320]bf16 @ W[Ncols,320]bf16^T (+bias)
// mode 0: p0 fp32 [row*320+col]
// mode 1: col<320 -> qe bf16 [B,N,320]; else ke bf16 [B,N,320]
// mode 2: q->p0 [B,H,N,64]bf16 (d>=40 zero-padded); k->p1 same; v->p2 [B,H,48,1024]bf16
// mode 3: p0 fp32 [(b*320+col)*1024+n] via LDS transpose
__global__ __launch_bounds__(256, 4) void k_mgemm(
    const unsigned short* __restrict__ A, const unsigned short* __restrict__ W,
    const float* __restrict__ bias, void* p0, void* p1, void* p2, int mode) {
  __shared__ float smem[64 * 65];     // mode-3 fp32 tile / mode-2 v-tile (ushort view)
  const int t = threadIdx.x, w = t >> 6, lane = t & 63;
  const int q16 = lane >> 4, l16 = lane & 15;
  const int rt = blockIdx.x * 64, jt = blockIdx.y * 64;
  f32x4 acc[4];
  #pragma unroll
  for (int i = 0; i < 4; ++i)
    #pragma unroll
    for (int j = 0; j < 4; ++j) acc[i][j] = 0.f;
  const unsigned short* ap = A + (size_t)(rt + 16 * w + l16) * 320 + q16 * 8;
  const unsigned short* wp = W + (size_t)(jt + l16) * 320 + q16 * 8;
  for (int kc = 0; kc < 10; ++kc) {
    bf8 af = *(const bf8*)(ap + kc * 32);
    #pragma unroll
    for (int ct = 0; ct < 4; ++ct) {
      bf8 bf = *(const bf8*)(wp + (size_t)ct * 16 * 320 + kc * 32);
      acc[ct] = mfma16(af, bf, acc[ct]);
    }
  }
  if (mode == 0 || mode == 1) {
    #pragma unroll
    for (int ct = 0; ct < 4; ++ct) {
      int col = jt + ct * 16 + l16;
      float bv = bias ? bias[col] : 0.f;
      #pragma unroll
      for (int r = 0; r < 4; ++r) {
        int row = rt + 16 * w + q16 * 4 + r;
        float v = acc[ct][r] + bv;
        if (mode == 0) {
          ((float*)p0)[(size_t)row * 320 + col] = v;
        } else {
          if (col < 320) ((unsigned short*)p0)[(size_t)row * 320 + col] = f2bf(v);
          else           ((unsigned short*)p1)[(size_t)row * 320 + col - 320] = f2bf(v);
        }
      }
    }
  } else if (mode == 2) {
    const int part = jt / 320;       // uniform per block (320 % 64 == 0)
    if (part < 2) {
      unsigned short* dst = (unsigned short*)(part == 0 ? p0 : p1);
      #pragma unroll
      for (int ct = 0; ct < 4; ++ct) {
        int col = jt + ct * 16 + l16;
        float bv = bias[col];
        int rem = col - part * 320;
        int h = rem / 40, d = rem % 40;
        #pragma unroll
        for (int r = 0; r < 4; ++r) {
          int row = rt + 16 * w + q16 * 4 + r;
          int b = row >> 10, n = row & 1023;
          size_t base = (((size_t)b * 8 + h) * 1024 + n) * 64;
          dst[base + d] = f2bf(acc[ct][r] + bv);
          if (d < 24) dst[base + 40 + d] = 0;   // zero the K-pad
        }
      }
    } else {
      // v: stage [col][n] ushort tile, then write [B,H,48,1024] coalesced
      unsigned short* vt_t = (unsigned short*)smem;       // [64][72]
      #pragma unroll
      for (int ct = 0; ct < 4; ++ct) {
        int col = jt + ct * 16 + l16;
        float bv = bias[col];
        #pragma unroll
        for (int r = 0; r < 4; ++r)
          vt_t[(ct * 16 + l16) * 72 + 16 * w + q16 * 4 + r] = f2bf(acc[ct][r] + bv);
      }
      __syncthreads();
      const int cl = t >> 2, seg = t & 3;
      int rem = (jt - 640) + cl;
      int h = rem / 40, d = rem % 40;
      int b = rt >> 10, n = (rt & 1023) + seg * 16;
      const float4* lp = (const float4*)&vt_t[cl * 72 + seg * 16];
      float4 a0 = lp[0], a1 = lp[1];
      float4* gp = (float4*)((unsigned short*)p2 +
                             (((size_t)b * 8 + h) * 48 + d) * 1024 + n);
      gp[0] = a0; gp[1] = a1;
    }
  } else {
    // mode 3: out[(b*320+col)*1024+n] via LDS transpose
    #pragma unroll
    for (int ct = 0; ct < 4; ++ct) {
      int col = jt + ct * 16 + l16;
      float bv = bias[col];
      #pragma unroll
      for (int r = 0; r < 4; ++r)
        smem[(16 * w + q16 * 4 + r) * 65 + ct * 16 + l16] = acc[ct][r] + bv;
    }
    __syncthreads();
    const int cl = t >> 2, seg = t & 3;
    int b = rt >> 10, n = (rt & 1023) + seg * 16;
    float* orow = (float*)p0 + ((size_t)b * 320 + jt + cl) * 1024 + n;
    #pragma unroll
    for (int i2 = 0; i2 < 4; ++i2) {
      float4 vv;
      vv.x = smem[(seg * 16 + i2 * 4 + 0) * 65 + cl];
      vv.y = smem[(seg * 16 + i2 * 4 + 1) * 65 + cl];
      vv.z = smem[(seg * 16 + i2 * 4 + 2) * 65 + cl];
      vv.w = smem[(seg * 16 + i2 * 4 + 3) * 65 + cl];
      ((float4*)orow)[i2] = vv;
    }
  }
}

// S[b,n,m] = (qe[b] @ ke[b]^T) * EDGE_SCALE   (batched MFMA GEMM, 512 blocks)
__global__ __launch_bounds__(256, 4) void k_sgemm(
    const unsigned short* __restrict__ qe, const unsigned short* __restrict__ ke,
    float* __restrict__ S) {
  const int t = threadIdx.x, w = t >> 6, lane = t & 63;
  const int q16 = lane >> 4, l16 = lane & 15;
  const int rt = blockIdx.x * 64, jt = blockIdx.y * 64, b = blockIdx.z;
  const unsigned short* A = qe + (size_t)b * 1024 * 320;
  const unsigned short* W = ke + (size_t)b * 1024 * 320;
  f32x4 acc[4];
  #pragma unroll
  for (int i = 0; i < 4; ++i)
    #pragma unroll
    for (int j = 0; j < 4; ++j) acc[i][j] = 0.f;
  const unsigned short* ap = A + (size_t)(rt + 16 * w + l16) * 320 + q16 * 8;
  const unsigned short* wp = W + (size_t)(jt + l16) * 320 + q16 * 8;
  for (int kc = 0; kc < 10; ++kc) {
    bf8 af = *(const bf8*)(ap + kc * 32);
    #pragma unroll
    for (int ct = 0; ct < 4; ++ct) {
      bf8 bf = *(const bf8*)(wp + (size_t)ct * 16 * 320 + kc * 32);
      acc[ct] = mfma16(af, bf, acc[ct]);
    }
  }
  #pragma unroll
  for (int ct = 0; ct < 4; ++ct)
    #pragma unroll
    for (int r = 0; r < 4; ++r)
      S[((size_t)b * 1024 + rt + 16 * w + q16 * 4 + r) * 1024 + jt + ct * 16 + l16] =
          acc[ct][r] * EDGE_SCALE;
}

// edge[row,:] = softmax(S[row,:])  (wave per row)
__global__ __launch_bounds__(256) void k_smax(const float* __restrict__ S,
                                              float* __restrict__ edge) {
  const int w = threadIdx.x >> 6, lane = threadIdx.x & 63;
  const int row = blockIdx.x * 4 + w;
  const float4* sp = (const float4*)(S + (size_t)row * 1024) + lane;
  float4 v[4];
  #pragma unroll
  for (int i = 0; i < 4; ++i) v[i] = sp[i * 64];
  float mx = -3.4e38f;
  #pragma unroll
  for (int i = 0; i < 4; ++i)
    mx = fmaxf(mx, fmaxf(fmaxf(v[i].x, v[i].y), fmaxf(v[i].z, v[i].w)));
  mx = wave_max(mx);
  float s = 0.f;
  #pragma unroll
  for (int i = 0; i < 4; ++i) {
    v[i].x = __expf(v[i].x - mx); v[i].y = __expf(v[i].y - mx);
    v[i].z = __expf(v[i].z - mx); v[i].w = __expf(v[i].w - mx);
    s += v[i].x + v[i].y + v[i].z + v[i].w;
  }
  s = wave_sum(s);
  float inv = 1.f / s;
  float4* ep = (float4*)(edge + (size_t)row * 1024) + lane;
  #pragma unroll
  for (int i = 0; i < 4; ++i)
    ep[i * 64] = make_float4(v[i].x * inv, v[i].y * inv, v[i].z * inv, v[i].w * inv);
}

// y_bf16 = LN(diag*LN(node)*s + LN(node)) per row; wave = 1 row.
__global__ __launch_bounds__(256) void k_ln(const float* __restrict__ node,
    const float* __restrict__ edge, const float* __restrict__ sv,
    const float* __restrict__ g1, const float* __restrict__ b1,
    const float* __restrict__ g2, const float* __restrict__ b2,
    unsigned short* __restrict__ y) {
  const int w = threadIdx.x >> 6, lane = threadIdx.x & 63;
  const int row = blockIdx.x * 4 + w;
  const int b = row >> 10, n = row & 1023;
  const float* xr = node + (size_t)row * 320;
  float x[5];
  #pragma unroll
  for (int i = 0; i < 5; ++i) x[i] = xr[lane + 64 * i];
  float s = x[0] + x[1] + x[2] + x[3] + x[4];
  float mean = wave_sum(s) * (1.f / 320.f);
  float v = 0.f;
  #pragma unroll
  for (int i = 0; i < 5; ++i) { float d = x[i] - mean; v += d * d; }
  float rstd = rsqrtf(wave_sum(v) * (1.f / 320.f) + LN_EPS);
  float diag = edge[(size_t)row * 1024 + n];
  float n2[5];
  #pragma unroll
  for (int i = 0; i < 5; ++i) {
    int c = lane + 64 * i;
    float nt = (x[i] - mean) * rstd * g1[c] + b1[c];
    n2[i] = diag * nt * sv[b * 320 + c] + nt;
  }
  s = n2[0] + n2[1] + n2[2] + n2[3] + n2[4];
  float mean2 = wave_sum(s) * (1.f / 320.f);
  v = 0.f;
  #pragma unroll
  for (int i = 0; i < 5; ++i) { float d = n2[i] - mean2; v += d * d; }
  float rstd2 = rsqrtf(wave_sum(v) * (1.f / 320.f) + LN_EPS);
  unsigned short* yr = y + (size_t)row * 320;
  #pragma unroll
  for (int i = 0; i < 5; ++i) {
    int c = lane + 64 * i;
    yr[c] = f2bf((n2[i] - mean2) * rstd2 * g2[c] + b2[c]);
  }
}

// Attention scores + AV per (b, h, 16-row tile). MFMA, grouped LDS pipeline.
// Structural note: exact softmax + th=rw*(a+S) requires holding 16x1024
// scores / 256 thr = 64 f32/thread (128 unified regs) -> 4 waves/SIMD cap;
// latency-bound at ~51 us. Measured alternatives (fusion/pair-split/
// recompute/grid-swizzle, R2-R7) all neutral or worse.
__global__ __launch_bounds__(256, 4) void k_score(
    const unsigned short* __restrict__ qbf, const unsigned short* __restrict__ kbf,
    const unsigned short* __restrict__ vtb, const float* __restrict__ edge,
    unsigned short* __restrict__ thbuf, float* __restrict__ att,
    const float* __restrict__ ew, const float* __restrict__ eb,
    const float* __restrict__ rw) {
  __shared__ unsigned short a_lds[4][4][16][20];  // [wave][tile-in-group][n-row][m pad]
  __shared__ unsigned short th_lds[4][16][72];    // [wave][n-row][64 m-cols pad72]
  __shared__ float ored[4][3][16][17];
  __shared__ float redm[4][16], reds[4][16];
  const int t = threadIdx.x, w = t >> 6, lane = t & 63;
  const int q16 = lane >> 4, l16 = lane & 15;
  const int n0 = blockIdx.x * 16, h = blockIdx.y, b = blockIdx.z;
  const size_t bh = (size_t)b * 8 + h;
  const unsigned short* qp = qbf + (bh * 1024 + n0 + l16) * 64 + q16 * 8;
  bf8 af0 = *(const bf8*)(qp);
  bf8 af1 = *(const bf8*)(qp + 32);
  f32x4 acc[16];
  #pragma unroll
  for (int i = 0; i < 16; ++i)
    #pragma unroll
    for (int j = 0; j < 4; ++j) acc[i][j] = 0.f;
  const unsigned short* kp = kbf + (bh * 1024 + (size_t)w * 256 + l16) * 64 + q16 * 8;
  #pragma unroll
  for (int tt = 0; tt < 16; ++tt) {
    const unsigned short* kpt = kp + (size_t)tt * 16 * 64;
    bf8 b0 = *(const bf8*)(kpt);
    bf8 b1 = *(const bf8*)(kpt + 32);
    acc[tt] = mfma16(af0, b0, acc[tt]);
    acc[tt] = mfma16(af1, b1, acc[tt]);
  }
  const float ewh = ew[h], ebh = eb[h], rwh = rw[h];
  const float* ep = edge + ((size_t)b * 1024 + n0 + q16 * 4) * 1024 + w * 256 + l16;
  #pragma unroll
  for (int tt = 0; tt < 16; ++tt)
    #pragma unroll
    for (int r = 0; r < 4; ++r) {
      float ev = ep[(size_t)r * 1024 + tt * 16];
      acc[tt][r] = fmaf(acc[tt][r], ATT_SCALE, fmaf(ev, ewh, ebh));
    }
  // block-wide row max
  float pm[4] = {-3.4e38f, -3.4e38f, -3.4e38f, -3.4e38f};
  #pragma unroll
  for (int tt = 0; tt < 16; ++tt)
    #pragma unroll
    for (int r = 0; r < 4; ++r) pm[r] = fmaxf(pm[r], acc[tt][r]);
  #pragma unroll
  for (int r = 0; r < 4; ++r)
    #pragma unroll
    for (int o = 1; o <= 8; o <<= 1) pm[r] = fmaxf(pm[r], __shfl_xor(pm[r], o));
  if (l16 == 0) {
    #pragma unroll
    for (int r = 0; r < 4; ++r) redm[w][q16 * 4 + r] = pm[r];
  }
  __syncthreads();
  float m[4], ps[4] = {0.f, 0.f, 0.f, 0.f};
  #pragma unroll
  for (int r = 0; r < 4; ++r)
    m[r] = fmaxf(fmaxf(redm[0][q16 * 4 + r], redm[1][q16 * 4 + r]),
                 fmaxf(redm[2][q16 * 4 + r], redm[3][q16 * 4 + r]));
  #pragma unroll
  for (int tt = 0; tt < 16; ++tt)
    #pragma unroll
    for (int r = 0; r < 4; ++r) ps[r] += __expf(acc[tt][r] - m[r]);
  #pragma unroll
  for (int r = 0; r < 4; ++r)
    #pragma unroll
    for (int o = 1; o <= 8; o <<= 1) ps[r] += __shfl_xor(ps[r], o);
  if (l16 == 0) {
    #pragma unroll
    for (int r = 0; r < 4; ++r) reds[w][q16 * 4 + r] = ps[r];
  }
  __syncthreads();
  float inv[4];
  #pragma unroll
  for (int r = 0; r < 4; ++r)
    inv[r] = 1.f / (reds[0][q16 * 4 + r] + reds[1][q16 * 4 + r] +
                    reds[2][q16 * 4 + r] + reds[3][q16 * 4 + r]);
  // grouped: a->LDS, th->LDS, AV-MFMA, th writeout (all per-wave private, no barrier)
  f32x4 oacc[3];
  #pragma unroll
  for (int i = 0; i < 3; ++i)
    #pragma unroll
    for (int j = 0; j < 4; ++j) oacc[i][j] = 0.f;
  unsigned short* tbase = thbuf + (bh * 1024 + n0) * 1024 + w * 256;
  const int trow = lane >> 2, tc4 = lane & 3;
  #pragma unroll
  for (int g = 0; g < 4; ++g) {
    #pragma unroll
    for (int ti = 0; ti < 4; ++ti) {
      int tt = g * 4 + ti;
      #pragma unroll
      for (int r = 0; r < 4; ++r) {
        float e = __expf(acc[tt][r] - m[r]);
        float a = e * inv[r];
        a_lds[w][ti][q16 * 4 + r][l16] = f2bf(a);
        th_lds[w][q16 * 4 + r][ti * 16 + l16] = f2bf(rwh * (a + acc[tt][r]));
      }
    }
    #pragma unroll
    for (int kk = 0; kk < 2; ++kk) {
      const unsigned short* ap2 = &a_lds[w][kk * 2 + (q16 >> 1)][l16][(q16 & 1) * 8];
      short4 lo = *(const short4*)(ap2);
      short4 hi = *(const short4*)(ap2 + 4);
      bf8 afv = {lo.x, lo.y, lo.z, lo.w, hi.x, hi.y, hi.z, hi.w};
      int kc = w * 8 + g * 2 + kk;
      const unsigned short* vp = vtb + (bh * 48 + l16) * 1024 + (size_t)kc * 32 + q16 * 8;
      #pragma unroll
      for (int nt = 0; nt < 3; ++nt) {
        bf8 bfv = *(const bf8*)(vp + (size_t)nt * 16 * 1024);
        oacc[nt] = mfma16(afv, bfv, oacc[nt]);
      }
    }
    {
      const float4* lp = (const float4*)&th_lds[w][trow][tc4 * 16];
      float4 v0 = lp[0], v1 = lp[1];
      float4* gp = (float4*)(tbase + (size_t)trow * 1024 + g * 64 + tc4 * 16);
      gp[0] = v0; gp[1] = v1;
    }
  }
  #pragma unroll
  for (int nt = 0; nt < 3; ++nt)
    #pragma unroll
    for (int r = 0; r < 4; ++r) ored[w][nt][q16 * 4 + r][l16] = oacc[nt][r];
  __syncthreads();
  #pragma unroll
  for (int k = 0; k < 3; ++k) {
    int o = k * 256 + t;
    int nt = o >> 8, row = (o >> 4) & 15, col = o & 15;
    int dim = nt * 16 + col;
    float sum = ored[0][nt][row][col] + ored[1][nt][row][col] +
                ored[2][nt][row][col] + ored[3][nt][row][col];
    if (dim < 40)
      att[((size_t)b * 1024 + n0 + row) * 320 + h * 40 + dim] = sum;
  }
}

// reduce thbuf over h -> t; edge += t; ws-softmax -> wsum; attbf = att + wsum (bf16)
__global__ __launch_bounds__(256) void k_wsum(
    const unsigned short* __restrict__ thbuf, float* __restrict__ edge,
    const float* __restrict__ att, unsigned short* __restrict__ attbf,
    const float* __restrict__ rb) {
  const int w = threadIdx.x >> 6, lane = threadIdx.x & 63;
  const int row = blockIdx.x * 4 + w;
  const int b = row >> 10, n = row & 1023;
  const float rbv = rb[0];
  float tv[16];
  #pragma unroll
  for (int i = 0; i < 16; ++i) tv[i] = rbv;
  #pragma unroll 1
  for (int h = 0; h < 8; ++h) {
    const unsigned short* tph = thbuf + (((size_t)b * 8 + h) * 1024 + n) * 1024 + lane * 4;
    #pragma unroll
    for (int seg = 0; seg < 4; ++seg) {
      ushort4 u = *(const ushort4*)(tph + seg * 256);
      tv[seg * 4 + 0] += bf2f(u.x);
      tv[seg * 4 + 1] += bf2f(u.y);
      tv[seg * 4 + 2] += bf2f(u.z);
      tv[seg * 4 + 3] += bf2f(u.w);
    }
  }
  float4* erp = (float4*)(edge + ((size_t)b * 1024 + n) * 1024) + lane;
  #pragma unroll
  for (int seg = 0; seg < 4; ++seg) {
    float4 e = erp[seg * 64];
    e.x += tv[seg * 4 + 0]; e.y += tv[seg * 4 + 1];
    e.z += tv[seg * 4 + 2]; e.w += tv[seg * 4 + 3];
    erp[seg * 64] = e;
  }
  float mx = -3.4e38f;
  #pragma unroll
  for (int i = 0; i < 16; ++i) mx = fmaxf(mx, tv[i]);
  mx = wave_max(mx);
  float s = 0.f, num = 0.f;
  #pragma unroll
  for (int i = 0; i < 16; ++i) {
    float e = __expf(tv[i] - mx);
    s += e; num += e * tv[i];
  }
  s = wave_sum(s); num = wave_sum(num);
  const float wsum = num / s;
  const float* ar = att + (size_t)row * 320;
  unsigned short* ao = attbf + (size_t)row * 320;
  #pragma unroll
  for (int i = 0; i < 5; ++i) {
    int c = lane + 64 * i;
    ao[c] = f2bf(ar[c] + wsum);
  }
}

extern "C" void kernel_launch(void* const* d_in, const int* in_sizes, int n_in,
                              void* d_out, int out_size, void* d_ws, size_t ws_size,
                              hipStream_t stream) {
  const float* x      = (const float*)d_in[0];
  const float* da     = (const float*)d_in[1];
  const float* qk_w   = (const float*)d_in[2];
  const float* fcp_w  = (const float*)d_in[3];
  const float* fcp_b  = (const float*)d_in[4];
  const float* ln1_g  = (const float*)d_in[5];
  const float* ln1_b  = (const float*)d_in[6];
  const float* gln_g  = (const float*)d_in[7];
  const float* gln_b  = (const float*)d_in[8];
  const float* qkv_w  = (const float*)d_in[9];
  const float* qkv_b  = (const float*)d_in[10];
  const float* proj_w = (const float*)d_in[11];
  const float* proj_b = (const float*)d_in[12];
  const float* exp_w  = (const float*)d_in[13];
  const float* exp_b  = (const float*)d_in[14];
  const float* red_w  = (const float*)d_in[15];
  const float* red_b  = (const float*)d_in[16];
  float* ws = (float*)d_ws;
  float* node  = ws + 0;                                   // 655360
  unsigned short* ybf   = (unsigned short*)(ws + 655360);  // 327680 fl
  float* attb  = ws + 983040;                              // 655360
  unsigned short* attbf = (unsigned short*)(ws + 1638400); // 327680 fl
  float* edge  = ws + 1966080;                             // 2097152
  float* svec  = ws + 4063232;                             // 640
  unsigned short* nodebf = (unsigned short*)(ws + 4063872);// 327680 fl
  unsigned short* qe   = (unsigned short*)(ws + 4391552);  // 327680 fl
  unsigned short* ke   = (unsigned short*)(ws + 4719232);  // 327680 fl
  unsigned short* qbf  = (unsigned short*)(ws + 5046912);  // 524288 fl
  unsigned short* kbf  = (unsigned short*)(ws + 5571200);  // 524288 fl
  unsigned short* vtb  = (unsigned short*)(ws + 6095488);  // 393216 fl
  unsigned short* wbf  = (unsigned short*)(ws + 6488704);  // 512000 fl
  unsigned short* thbuf= (unsigned short*)(ws + 7000704);  // 8388608 fl
  float* sbuf = ws + 15389312;                             // 2097152
  float* out = (float*)d_out;
  unsigned short* qk_wb   = wbf;
  unsigned short* qkv_wb  = wbf + 204800;
  unsigned short* proj_wb = wbf + 819200;

  hipLaunchKernelGGL(k_trans, dim3(32, 10, 2), dim3(256), 0, stream, x, node, nodebf);
  hipLaunchKernelGGL(k_svec, dim3(2), dim3(320), 0, stream, da, fcp_w, fcp_b, svec);
  hipLaunchKernelGGL(k_wcvt, dim3(512), dim3(256), 0, stream,
                     qk_w, 204800, qkv_w, 614400, proj_w, 204800, wbf);
  hipLaunchKernelGGL(k_mgemm, dim3(32, 10), dim3(256), 0, stream,
                     nodebf, qk_wb, (const float*)nullptr, qe, ke, (void*)nullptr, 1);
  hipLaunchKernelGGL(k_sgemm, dim3(16, 16, 2), dim3(256), 0, stream, qe, ke, sbuf);
  hipLaunchKernelGGL(k_smax, dim3(512), dim3(256), 0, stream, sbuf, edge);
  for (int l = 0; l < 2; ++l) {
    hipLaunchKernelGGL(k_ln, dim3(512), dim3(256), 0, stream, node, edge, svec,
                       ln1_g + l * 320, ln1_b + l * 320, gln_g + l * 320, gln_b + l * 320, ybf);
    hipLaunchKernelGGL(k_mgemm, dim3(32, 15), dim3(256), 0, stream,
                       ybf, qkv_wb + (size_t)l * 307200, qkv_b + l * 960, qbf, kbf, vtb, 2);
    hipLaunchKernelGGL(k_score, dim3(64, 8, 2), dim3(256), 0, stream,
                       qbf, kbf, vtb, edge, thbuf, attb,
                       exp_w + l * 8, exp_b + l * 8, red_w + l * 8);
    hipLaunchKernelGGL(k_wsum, dim3(512), dim3(256), 0, stream,
                       thbuf, edge, attb, attbf, red_b + l);
    if (l == 0)
      hipLaunchKernelGGL(k_mgemm, dim3(32, 5), dim3(256), 0, stream,
                         attbf, proj_wb, proj_b, node, (void*)nullptr, (void*)nullptr, 0);
    else
      hipLaunchKernelGGL(k_mgemm, dim3(32, 5), dim3(256), 0, stream,
                         attbf, proj_wb + 102400, proj_b + 320, out,
                         (void*)nullptr, (void*)nullptr, 3);
  }
}